// Round 19
// baseline (2452.072 us; speedup 1.0000x reference)
//
#include <hip/hip_runtime.h>
#include <hip/hip_bf16.h>
#include <hip/hip_fp8.h>
#include <math.h>

#define N_NODES 32768
#define N_EDGES 262144
#define N_GRAPHS 512
#define IN_DIM 300
#define KPAD 320
#define HID 128
#define HEADS 4
#define D_FUSED 512
#define N_LAYERS 3

typedef __hip_bfloat16 bf16;
typedef short bf16x8 __attribute__((ext_vector_type(8)));
typedef short bf16x4 __attribute__((ext_vector_type(4)));
typedef float f32x4 __attribute__((ext_vector_type(4)));
typedef float f32x2 __attribute__((ext_vector_type(2)));

__device__ __forceinline__ float bfs_to_f(short s)
{
    unsigned u = ((unsigned)(unsigned short)s) << 16;
    return __builtin_bit_cast(float, u);
}

__device__ __forceinline__ short f_to_bfs(float v)
{
    return (short)__builtin_bit_cast(unsigned short, __float2bfloat16(v));
}

__device__ __forceinline__ void bf8_to_f32(bf16x8 v, float* f)
{
#pragma unroll
    for (int j = 0; j < 8; ++j) f[j] = bfs_to_f(v[j]);
}

__device__ __forceinline__ unsigned char f32_to_fp8(float v)
{
#if __has_builtin(__builtin_amdgcn_cvt_pk_fp8_f32)
    int p = __builtin_amdgcn_cvt_pk_fp8_f32(v, v, 0, false);
    return (unsigned char)(p & 0xff);
#else
    __hip_fp8_e4m3 t(v);
    return (unsigned char)t.__x;
#endif
}

__device__ __forceinline__ void fp8x8_to_f32(uint2 w, float* f)
{
#if __has_builtin(__builtin_amdgcn_cvt_pk_f32_fp8)
    f32x2 a = __builtin_amdgcn_cvt_pk_f32_fp8((int)w.x, false);
    f32x2 b = __builtin_amdgcn_cvt_pk_f32_fp8((int)w.x, true);
    f32x2 c = __builtin_amdgcn_cvt_pk_f32_fp8((int)w.y, false);
    f32x2 d = __builtin_amdgcn_cvt_pk_f32_fp8((int)w.y, true);
    f[0] = a.x; f[1] = a.y; f[2] = b.x; f[3] = b.y;
    f[4] = c.x; f[5] = c.y; f[6] = d.x; f[7] = d.y;
#else
    const unsigned char* p = (const unsigned char*)&w;
#pragma unroll
    for (int j = 0; j < 8; ++j) {
        __hip_fp8_e4m3 t;
        t.__x = (__hip_fp8_storage_t)p[j];
        f[j] = (float)t;
    }
#endif
}

__device__ __forceinline__ void gload_lds16(const void* g, void* l)
{
    __builtin_amdgcn_global_load_lds(
        (const __attribute__((address_space(1))) void*)g,
        (__attribute__((address_space(3))) void*)l, 16, 0, 0);
}

// ---------------------------------------------------------------------------
// 256x256-tile MFMA GEMM (round-16 base: BK=64, 2 barriers/K-tile, counted
// vmcnt(2)). ROUND-19: per-wave ROTATED quadrant order q = (qq+wid)&3 —
// de-bursts the post-barrier LDS-read storm (kernel is LDS-read-traffic
// bound: 192 KB frag reads vs 620 cyc MFMA per tile). Staging stays in qq
// order (each part staged once); acc indexed by actual q.
// EPI=0: col<csplit -> C0 (bf16, ldc0), else C1 (bf16, ldc1, col-csplit).
// EPI=1: bcol<512 -> C0 bf16 (ld ldc0); else -> C2 fp8 e4m3, ld 1536,
//        at col-512 (unified q|k|v fp8 buffer).
// Requires M%256==0, N%256==0, K%64==0, K>=128, 16B-aligned rows.
// ---------------------------------------------------------------------------
template <int K, int ACT, int EPI>
__global__ __launch_bounds__(512, 2) void mfma_gemm256(
    const bf16* __restrict__ A, int lda,
    const bf16* __restrict__ Bt,
    const float* __restrict__ bias,
    bf16* __restrict__ C0, int ldc0,
    bf16* __restrict__ C1, int ldc1, int csplit,
    unsigned char* __restrict__ C2,
    int nbx)
{
    __shared__ __align__(16) char lds[131072];
    // slab(buf, mat, half) = buf*65536 + mat*32768 + half*16384

    const int t = threadIdx.x;
    const int wid = t >> 6, lane = t & 63;
    const int hi = lane >> 4, li = lane & 15;
    const int wr = wid >> 2, wc = wid & 3;

    int wg = blockIdx.x;
    if ((gridDim.x & 7) == 0) {              // bijective XCD swizzle
        const int cpx = gridDim.x >> 3;
        wg = (wg & 7) * cpx + (wg >> 3);
    }
    const int mb = wg / nbx, nb = wg % nbx;
    const int brow = mb * 256, bcol = nb * 256;
    constexpr int NT = K >> 6;

    const int row0 = t >> 3, sl0 = (((t & 7) ^ (row0 & 7)) * 8);
    const int c1i = t + 512;
    const int row1 = c1i >> 3, sl1 = (((c1i & 7) ^ (row1 & 7)) * 8);

    // part q: 0 = A-half0, 1 = A-half1, 2 = B-half0, 3 = B-half1
    const bf16* srcs[4][2];
    srcs[0][0] = A  + (size_t)(brow + row0)       * lda + sl0;
    srcs[0][1] = A  + (size_t)(brow + row1)       * lda + sl1;
    srcs[1][0] = A  + (size_t)(brow + 128 + row0) * lda + sl0;
    srcs[1][1] = A  + (size_t)(brow + 128 + row1) * lda + sl1;
    srcs[2][0] = Bt + (size_t)(bcol + row0)       * K   + sl0;
    srcs[2][1] = Bt + (size_t)(bcol + row1)       * K   + sl1;
    srcs[3][0] = Bt + (size_t)(bcol + 128 + row0) * K   + sl0;
    srcs[3][1] = Bt + (size_t)(bcol + 128 + row1) * K   + sl1;

    auto stage_part = [&](int buf, int kt1, int q) {
        const int ko = kt1 * 64;
        const int slab = buf * 65536 + (q >> 1) * 32768 + (q & 1) * 16384;
        gload_lds16(srcs[q][0] + ko, lds + slab + wid * 1024);
        gload_lds16(srcs[q][1] + ko, lds + slab + 8192 + wid * 1024);
    };

    f32x4 acc[8][4] = {};

#pragma unroll
    for (int q = 0; q < 4; ++q) stage_part(0, 0, q);

#pragma unroll
    for (int kt = 0; kt < NT; ++kt) {
        const int b = kt & 1;
        const char* Aslab = lds + b * 65536;
        const char* Bslab = lds + b * 65536 + 32768 + (wc >> 1) * 16384;
        const int bRow0 = (wc & 1) * 64;

        if (kt < NT - 1) {
            stage_part(b ^ 1, kt + 1, 0);
            asm volatile("s_waitcnt vmcnt(2)" ::: "memory");
        } else {
            asm volatile("s_waitcnt vmcnt(0)" ::: "memory");
        }
        __builtin_amdgcn_s_barrier();        // all waves' DMA for tile kt landed
        __builtin_amdgcn_sched_barrier(0);

        bf16x8 bfrag[4][2];
#pragma unroll
        for (int n = 0; n < 4; ++n)
#pragma unroll
            for (int ks = 0; ks < 2; ++ks) {
                const int row = bRow0 + n * 16 + li;
                bfrag[n][ks] = *(const bf16x8*)(
                    Bslab + row * 128 + (((ks * 4 + hi) ^ (row & 7)) << 4));
            }

        // 4 MFMA quadrants, ROTATED per wave (q = (qq+wid)&3): de-bursts the
        // LDS-read storm; no intermediate barriers (per-wave lgkmcnt orders
        // each wave's reads vs its MFMAs; waves slip and overlap freely).
#pragma unroll
        for (int qq = 0; qq < 4; ++qq) {
            if (qq > 0 && kt < NT - 1) stage_part(b ^ 1, kt + 1, qq);
            const int q = (qq + wid) & 3;
            // A-frag rows live in half q>>1 of the A slabs at (q&1)*... :
            // row = wr*128 + q*32 + mm*16 spans rows [0,256) split across the
            // two A half-slabs; compute absolute row then pick the half.
            bf16x8 af[2][2];
#pragma unroll
            for (int mm = 0; mm < 2; ++mm)
#pragma unroll
                for (int ks = 0; ks < 2; ++ks) {
                    const int arow = wr * 128 + (q * 2 + mm) * 16 + li;
                    const char* slab = Aslab + (arow >> 7) * 16384;
                    const int row = arow & 127;
                    af[mm][ks] = *(const bf16x8*)(
                        slab + row * 128 + (((ks * 4 + hi) ^ (row & 7)) << 4));
                }
            __builtin_amdgcn_s_setprio(1);
#pragma unroll
            for (int ks = 0; ks < 2; ++ks)
#pragma unroll
                for (int mm = 0; mm < 2; ++mm)
#pragma unroll
                    for (int n = 0; n < 4; ++n)
                        acc[q * 2 + mm][n] = __builtin_amdgcn_mfma_f32_16x16x32_bf16(
                            af[mm][ks], bfrag[n][ks], acc[q * 2 + mm][n], 0, 0, 0);
            __builtin_amdgcn_s_setprio(0);
        }

        // tile end: buf b fully consumed before tile kt+1 stages kt+2 into it
        __builtin_amdgcn_s_barrier();
        __builtin_amdgcn_sched_barrier(0);
    }

    // epilogue: C/D layout col=li, row=hi*4+r; destination block-uniform
    if (EPI == 0) {
        const bool lo = (bcol < csplit);
        bf16* Cd = lo ? C0 : C1;
        const int ldc = lo ? ldc0 : ldc1;
        const int csub = lo ? 0 : csplit;
#pragma unroll
        for (int m = 0; m < 8; ++m)
#pragma unroll
            for (int n = 0; n < 4; ++n) {
                const int col = bcol + wc * 64 + n * 16 + li;
                const float bv = bias[col];
#pragma unroll
                for (int r = 0; r < 4; ++r) {
                    const int row = brow + wr * 128 + m * 16 + hi * 4 + r;
                    float v = acc[m][n][r] + bv;
                    if (ACT == 1) v = fmaxf(v, 0.f);
                    Cd[(size_t)row * ldc + (col - csub)] = __float2bfloat16(v);
                }
            }
    } else if (bcol < 512) {
#pragma unroll
        for (int m = 0; m < 8; ++m)
#pragma unroll
            for (int n = 0; n < 4; ++n) {
                const int col = bcol + wc * 64 + n * 16 + li;
                const float bv = bias[col];
#pragma unroll
                for (int r = 0; r < 4; ++r) {
                    const int row = brow + wr * 128 + m * 16 + hi * 4 + r;
                    C0[(size_t)row * ldc0 + col] = __float2bfloat16(acc[m][n][r] + bv);
                }
            }
    } else {
        // fp8 q|k|v unified buffer, ld 1536, at col-512
#pragma unroll
        for (int m = 0; m < 8; ++m)
#pragma unroll
            for (int n = 0; n < 4; ++n) {
                const int col = bcol + wc * 64 + n * 16 + li;
                const float bv = bias[col];
#pragma unroll
                for (int r = 0; r < 4; ++r) {
                    const int row = brow + wr * 128 + m * 16 + hi * 4 + r;
                    C2[(size_t)row * 1536 + (col - 512)] = f32_to_fp8(acc[m][n][r] + bv);
                }
            }
    }
}

// ---------------------------------------------------------------------------
// 128x128 MFMA GEMM (m97 structure) — kept for the small-N encoder GEMM.
// ---------------------------------------------------------------------------
template <int ACT>
__global__ __launch_bounds__(256) void mfma_gemm(
    const bf16* __restrict__ A, int lda,
    const bf16* __restrict__ Bt,
    const float* __restrict__ bias,
    bf16* __restrict__ C, int ldc, int K)
{
    __shared__ __align__(16) char lds[16384];
    char* As = lds;
    char* Bs = lds + 8192;

    const int t = threadIdx.x;
    const int wid = t >> 6, lane = t & 63;
    const int brow = blockIdx.x * 128;
    const int bcol = blockIdx.y * 128;
    const int wr = wid >> 1, wc = wid & 1;

    f32x4 acc[4][4] = {};

    for (int k0 = 0; k0 < K; k0 += 32) {
#pragma unroll
        for (int j = 0; j < 2; ++j) {
            const int seg = wid * 2 + j;
            const int row = seg * 16 + (lane >> 2);
            const int clin = lane & 3;
            const int clog = clin ^ ((row >> 1) & 3);
            gload_lds16(A + (size_t)(brow + row) * lda + k0 + clog * 8,
                        As + seg * 1024);
            gload_lds16(Bt + (size_t)(bcol + row) * K + k0 + clog * 8,
                        Bs + seg * 1024);
        }
        __syncthreads();

        bf16x8 af[4], bfr[4];
#pragma unroll
        for (int m = 0; m < 4; ++m) {
            const int row = wr * 64 + m * 16 + (lane & 15);
            const int cl = (lane >> 4) ^ ((row >> 1) & 3);
            af[m] = *(const bf16x8*)(As + row * 64 + cl * 16);
        }
#pragma unroll
        for (int n = 0; n < 4; ++n) {
            const int row = wc * 64 + n * 16 + (lane & 15);
            const int cl = (lane >> 4) ^ ((row >> 1) & 3);
            bfr[n] = *(const bf16x8*)(Bs + row * 64 + cl * 16);
        }
#pragma unroll
        for (int m = 0; m < 4; ++m)
#pragma unroll
            for (int n = 0; n < 4; ++n)
                acc[m][n] = __builtin_amdgcn_mfma_f32_16x16x32_bf16(
                    af[m], bfr[n], acc[m][n], 0, 0, 0);
        __syncthreads();
    }

#pragma unroll
    for (int m = 0; m < 4; ++m) {
#pragma unroll
        for (int n = 0; n < 4; ++n) {
            const int col = bcol + wc * 64 + n * 16 + (lane & 15);
            const float bv = bias[col];
#pragma unroll
            for (int r = 0; r < 4; ++r) {
                const int row = brow + wr * 64 + m * 16 + (lane >> 4) * 4 + r;
                float v = acc[m][n][r] + bv;
                if (ACT == 1) v = fmaxf(v, 0.f);
                C[(size_t)row * ldc + col] = __float2bfloat16(v);
            }
        }
    }
}

// ---------------------------------------------------------------------------
// Weight/input prep
// ---------------------------------------------------------------------------
// Vectorized pad+cast: 300 = 75 float4 exactly; quads 75..79 are zero pad.
__global__ void prep_xpad_kernel(const float* __restrict__ x, bf16* __restrict__ xb)
{
    const int idx = blockIdx.x * 256 + threadIdx.x;   // grid covers N*80 exactly
    const int n = idx / 80, q = idx % 80;
    bf16x4 o;
    if (q < 75) {
        const float4 v = *(const float4*)(x + (size_t)n * IN_DIM + q * 4);
        o[0] = f_to_bfs(v.x); o[1] = f_to_bfs(v.y);
        o[2] = f_to_bfs(v.z); o[3] = f_to_bfs(v.w);
    } else {
        o[0] = 0; o[1] = 0; o[2] = 0; o[3] = 0;
    }
    *(bf16x4*)(xb + (size_t)n * KPAD + q * 4) = o;
}

__global__ void prep_encw_kernel(const float* __restrict__ syn_w,
                                 const float* __restrict__ ant_w,
                                 bf16* __restrict__ wt)
{
    const int c = blockIdx.x, k = threadIdx.x;
    float v = 0.f;
    if (k < IN_DIM) v = (c < HID) ? syn_w[k * HID + c] : ant_w[k * HID + (c - HID)];
    wt[c * KPAD + k] = __float2bfloat16(v);
}

__global__ void prep_fusw_kernel(const float* __restrict__ fw, bf16* __restrict__ wt)
{
    const int c = blockIdx.x, k = threadIdx.x;
    wt[c * 256 + k] = __float2bfloat16(fw[k * D_FUSED + c]);
}

__global__ __launch_bounds__(256) void prep_combw_kernel(
    const float* __restrict__ Wskip,
    const float* __restrict__ Wq,
    const float* __restrict__ Wk,
    const float* __restrict__ Wv,
    bf16* __restrict__ wt)
{
    __shared__ float tile[32][33];
    const int blk = blockIdx.x;
    const int l = blk >> 10, rem = blk & 1023;   // 64*16 = 1024 per layer
    const int cb = rem >> 4, kb = rem & 15;
    const int c0 = cb * 32;

    const int sel = c0 >> 9;
    const float* mat = (sel == 0) ? Wskip : (sel == 1) ? Wq : (sel == 2) ? Wk : Wv;
    const int cp0 = c0 & 511;

    const int j = threadIdx.x & 31;    // fast dim
    const int i0 = threadIdx.x >> 5;   // 0..7
#pragma unroll
    for (int s = 0; s < 4; ++s) {
        const int i = i0 + 8 * s;      // k within tile
        tile[i][j] = mat[((size_t)l * 512 + kb * 32 + i) * 512 + cp0 + j];
    }
    __syncthreads();
#pragma unroll
    for (int s = 0; s < 4; ++s) {
        const int jj = i0 + 8 * s;     // c within tile
        wt[((size_t)l * 2048 + c0 + jj) * 512 + kb * 32 + j] =
            __float2bfloat16(tile[j][jj]);
    }
}

__global__ void prep_bias_kernel(const float* __restrict__ syn_b,
                                 const float* __restrict__ ant_b,
                                 const float* __restrict__ bskip,
                                 const float* __restrict__ bq,
                                 const float* __restrict__ bk,
                                 const float* __restrict__ bv,
                                 float* __restrict__ benc,
                                 float* __restrict__ bcomb)
{
    const int i = blockIdx.x * 256 + threadIdx.x;
    if (i < 256) benc[i] = (i < HID) ? syn_b[i] : ant_b[i - HID];
    const int j = i - 256;
    if (j >= 0 && j < 6144) {
        const int l = j >> 11, c = j & 2047;
        const int sel = c >> 9, col = c & 511;
        const float* s = (sel == 0) ? bskip : (sel == 1) ? bq : (sel == 2) ? bk : bv;
        bcomb[j] = s[l * D_FUSED + col];
    }
}

// ---------------------------------------------------------------------------
// CSR build
// ---------------------------------------------------------------------------
__global__ void zero_int_kernel(int* __restrict__ p, int n)
{
    int i = blockIdx.x * 256 + threadIdx.x;
    if (i < n) p[i] = 0;
}

__global__ void hist_kernel(const int* __restrict__ dst, int* __restrict__ deg, int E)
{
    int e = blockIdx.x * 256 + threadIdx.x;
    if (e < E) atomicAdd(&deg[dst[e]], 1);
}

__global__ __launch_bounds__(256) void partial_sum_kernel(const int* __restrict__ deg,
                                                          int* __restrict__ part)
{
    int v = deg[blockIdx.x * 256 + threadIdx.x];
#pragma unroll
    for (int o = 32; o; o >>= 1) v += __shfl_xor(v, o);
    __shared__ int w4[4];
    if ((threadIdx.x & 63) == 0) w4[threadIdx.x >> 6] = v;
    __syncthreads();
    if (threadIdx.x == 0) part[blockIdx.x] = w4[0] + w4[1] + w4[2] + w4[3];
}

__global__ __launch_bounds__(128) void scan_part_kernel(int* __restrict__ part)
{
    __shared__ int s[128];
    const int t = threadIdx.x;
    s[t] = part[t];
    __syncthreads();
    for (int o = 1; o < 128; o <<= 1) {
        int v = (t >= o) ? s[t - o] : 0;
        __syncthreads();
        s[t] += v;
        __syncthreads();
    }
    part[t] = (t == 0) ? 0 : s[t - 1];  // exclusive
}

__global__ __launch_bounds__(256) void off_kernel(const int* __restrict__ deg,
                                                  const int* __restrict__ part,
                                                  int* __restrict__ off)
{
    __shared__ int s[256];
    const int b = blockIdx.x, t = threadIdx.x;
    s[t] = deg[b * 256 + t];
    __syncthreads();
    for (int o = 1; o < 256; o <<= 1) {
        int v = (t >= o) ? s[t - o] : 0;
        __syncthreads();
        s[t] += v;
        __syncthreads();
    }
    const int excl = (t == 0) ? 0 : s[t - 1];
    off[b * 256 + t] = part[b] + excl;
    if (b == 127 && t == 255) off[N_NODES] = part[127] + s[255];
}

__global__ void scatter_kernel(const int* __restrict__ src, const int* __restrict__ dst,
                               const int* __restrict__ off, int* __restrict__ cursor,
                               int* __restrict__ csr_src, int E)
{
    int e = blockIdx.x * 256 + threadIdx.x;
    if (e < E) {
        int d = dst[e];
        int pos = atomicAdd(&cursor[d], 1);
        csr_src[off[d] + pos] = src[e];
    }
}

// ---------------------------------------------------------------------------
// 8-edge/iteration attention as TWO independent 4-edge sets; no online max
// (shift-invariant, logits bounded << 1). All of q,k,v fp8 in one
// [N][1536] buffer: q at +0, k at +512, v at +1024 (each hd*128+dim).
// Block = 256 = 4 waves; wave = head hd of node blockIdx.x.
// Wave = 4 groups x 16 lanes; group g handles edges e0+g (set A) and
// e0+4+g (set B). Lane sub holds head dims sub*8..sub*8+7.
// hout holds skip projection; add attention, relu, write back.
// ---------------------------------------------------------------------------
__global__ __launch_bounds__(256) void attn_kernel(
    const unsigned char* __restrict__ qkvb, bf16* __restrict__ hout,
    const int* __restrict__ off, const int* __restrict__ csr)
{
    const int n = blockIdx.x;
    const int hd = threadIdx.x >> 6;
    const int lane = threadIdx.x & 63;
    const int g = lane >> 4, sub = lane & 15;
    const float scale = 0.08838834764831845f;  // 1/sqrt(128)

    float qf[8];
    fp8x8_to_f32(*(const uint2*)(qkvb + (size_t)n * 1536 + hd * 128 + sub * 8), qf);

    float zA = 0.f, zB = 0.f;
    float accA[8] = {}, accB[8] = {};

    const int s0 = off[n], s1 = off[n + 1];
    for (int e0 = s0; e0 < s1; e0 += 8) {
        const int ea = e0 + g;
        const int eb = e0 + 4 + g;
        const bool va = (ea < s1);
        const bool vb = (eb < s1);
        const int sa = va ? csr[ea] : 0;
        const int sb = vb ? csr[eb] : 0;
        const unsigned char* pa = qkvb + (size_t)sa * 1536 + hd * 128 + sub * 8;
        const unsigned char* pb = qkvb + (size_t)sb * 1536 + hd * 128 + sub * 8;

        // issue all 4 loads up front (16 gathers in flight across the wave)
        const uint2 kwa = *(const uint2*)(pa + 512);
        const uint2 kwb = *(const uint2*)(pb + 512);
        const uint2 vwa = *(const uint2*)(pa + 1024);
        const uint2 vwb = *(const uint2*)(pb + 1024);

        float kfa[8], kfb[8];
        fp8x8_to_f32(kwa, kfa);
        fp8x8_to_f32(kwb, kfb);
        float da = 0.f, db = 0.f;
#pragma unroll
        for (int j = 0; j < 8; ++j) {
            da = fmaf(qf[j], kfa[j], da);
            db = fmaf(qf[j], kfb[j], db);
        }
        // two independent shuffle chains, interleaved
        da += __shfl_xor(da, 1);  db += __shfl_xor(db, 1);
        da += __shfl_xor(da, 2);  db += __shfl_xor(db, 2);
        da += __shfl_xor(da, 4);  db += __shfl_xor(db, 4);
        da += __shfl_xor(da, 8);  db += __shfl_xor(db, 8);

        const float wa = va ? __expf(da * scale) : 0.f;
        const float wb = vb ? __expf(db * scale) : 0.f;
        zA += wa;
        zB += wb;

        float vfa[8], vfb[8];
        fp8x8_to_f32(vwa, vfa);
        fp8x8_to_f32(vwb, vfb);
#pragma unroll
        for (int j = 0; j < 8; ++j) {
            accA[j] = fmaf(wa, vfa[j], accA[j]);
            accB[j] = fmaf(wb, vfb[j], accB[j]);
        }
    }

    // set merge: plain register adds (free), then the 4-group merge
    float zz = zA + zB;
    zz += __shfl_xor(zz, 16);
    zz += __shfl_xor(zz, 32);
    const float inv = 1.f / (zz + 1e-16f);

    float o[8];
#pragma unroll
    for (int j = 0; j < 8; ++j) {
        float a = accA[j] + accB[j];
        a += __shfl_xor(a, 16);
        a += __shfl_xor(a, 32);
        o[j] = a * inv;
    }

    if (g == 0) {
        const size_t ob = (size_t)n * D_FUSED + hd * HID + sub * 8;
        const bf16x8 sk = *(const bf16x8*)(hout + ob);
        bf16x8 res;
#pragma unroll
        for (int j = 0; j < 8; ++j)
            res[j] = f_to_bfs(fmaxf(o[j] + bfs_to_f(sk[j]), 0.f));
        *(bf16x8*)(hout + ob) = res;
    }
}

// ---------------------------------------------------------------------------
// Mean-pool, vectorized: 4 node-lanes (waves) x 64 dim-lanes x bf16x8.
// ---------------------------------------------------------------------------
__global__ __launch_bounds__(256) void pool_kernel(const bf16* __restrict__ h,
                                                   const int* __restrict__ batch,
                                                   float* __restrict__ pooled)
{
    const int g = blockIdx.x;
    int a = 0, b = N_NODES;
    while (a < b) { int mid = (a + b) >> 1; if (batch[mid] < g) a = mid + 1; else b = mid; }
    const int start = a;
    b = N_NODES;
    while (a < b) { int mid = (a + b) >> 1; if (batch[mid] < g + 1) a = mid + 1; else b = mid; }
    const int end = a;
    const float invc = 1.f / fmaxf((float)(end - start), 1.f);

    const int nl = threadIdx.x >> 6;   // node lane (wave)
    const int dl = threadIdx.x & 63;   // dim lane: dims dl*8..dl*8+7

    float s[8] = {};
    for (int nidx = start + nl; nidx < end; nidx += 4) {
        const bf16x8 v = *(const bf16x8*)(h + (size_t)nidx * D_FUSED + dl * 8);
#pragma unroll
        for (int j = 0; j < 8; ++j) s[j] += bfs_to_f(v[j]);
    }

    __shared__ float red[4][512];
#pragma unroll
    for (int j = 0; j < 8; ++j) red[nl][dl * 8 + j] = s[j];
    __syncthreads();
    if (nl == 0) {
#pragma unroll
        for (int j = 0; j < 8; ++j) {
            const int d = dl * 8 + j;
            pooled[(size_t)g * D_FUSED + d] =
                (red[0][d] + red[1][d] + red[2][d] + red[3][d]) * invc;
        }
    }
}

__global__ __launch_bounds__(128) void cls_kernel(const float* __restrict__ pooled,
                                                  const float* __restrict__ w1,
                                                  const float* __restrict__ b1,
                                                  const float* __restrict__ w2,
                                                  const float* __restrict__ b2,
                                                  float* __restrict__ out)
{
    const int g = blockIdx.x;
    const int j = threadIdx.x;
    const float* p = pooled + (size_t)g * D_FUSED;
    float acc = 0.f;
    for (int i = 0; i < D_FUSED; ++i) acc += p[i] * w1[i * HID + j];
    const float hid = fmaxf(acc + b1[j], 0.f);
    float val = hid * w2[j];
#pragma unroll
    for (int o = 32; o; o >>= 1) val += __shfl_xor(val, o);
    __shared__ float ws2[2];
    if ((threadIdx.x & 63) == 0) ws2[threadIdx.x >> 6] = val;
    __syncthreads();
    if (threadIdx.x == 0) {
        const float sum = ws2[0] + ws2[1] + b2[0];
        out[g] = 1.f / (1.f + __expf(-sum));
    }
}

// ---------------------------------------------------------------------------
extern "C" void kernel_launch(void* const* d_in, const int* in_sizes, int n_in,
                              void* d_out, int out_size, void* d_ws, size_t ws_size,
                              hipStream_t stream)
{
    const float* x        = (const float*)d_in[0];
    const int*   ei       = (const int*)d_in[1];
    const int*   batch    = (const int*)d_in[2];
    const float* syn_w    = (const float*)d_in[3];
    const float* syn_b    = (const float*)d_in[4];
    const float* ant_w    = (const float*)d_in[5];
    const float* ant_b    = (const float*)d_in[6];
    const float* fusion_w = (const float*)d_in[7];
    const float* fusion_b = (const float*)d_in[8];
    const float* Wq       = (const float*)d_in[9];
    const float* bq       = (const float*)d_in[10];
    const float* Wk       = (const float*)d_in[11];
    const float* bk       = (const float*)d_in[12];
    const float* Wv       = (const float*)d_in[13];
    const float* bv       = (const float*)d_in[14];
    const float* Wskip    = (const float*)d_in[15];
    const float* bskip    = (const float*)d_in[16];
    const float* cls_w1   = (const float*)d_in[17];
    const float* cls_b1   = (const float*)d_in[18];
    const float* cls_w2   = (const float*)d_in[19];
    const float* cls_b2   = (const float*)d_in[20];

    const int* src = ei;
    const int* dst = ei + N_EDGES;

    // ---- workspace layout (~125 MB) ----
    const size_t NV = (size_t)N_NODES * D_FUSED;
    bf16* hA    = (bf16*)d_ws;                         // N*512 bf16
    bf16* hB    = hA + NV;                             // N*512 bf16
    unsigned char* qkv = (unsigned char*)(hB + NV);    // N*1536 fp8 (q|k|v)
    bf16* wenc  = (bf16*)(qkv + (size_t)N_NODES * 1536);     // 256*320
    bf16* wfus  = wenc + 256 * KPAD;                   // 512*256
    bf16* wcomb = wfus + 512 * 256;                    // 3*2048*512
    float* benc = (float*)(wcomb + (size_t)3 * 2048 * 512);  // 256
    float* bcomb = benc + 256;                         // 6144
    float* pooled = bcomb + 6144;                      // G*512
    int* deg    = (int*)(pooled + (size_t)N_GRAPHS * D_FUSED);
    int* cursor = deg + N_NODES;
    int* part   = cursor + N_NODES;                    // 128
    int* off    = part + 128;                          // N+1
    int* csr    = off + N_NODES + 1;                   // E

    bf16* xb   = (bf16*)qkv;  // N*320 bf16 (40MB < 48MB), dead before layer GEMMs
    bf16* tenc = hB;          // N*256, dead before first layer GEMM

    // ---- CSR build ----
    zero_int_kernel<<<(2 * N_NODES + 255) / 256, 256, 0, stream>>>(deg, 2 * N_NODES);
    hist_kernel<<<N_EDGES / 256, 256, 0, stream>>>(dst, deg, N_EDGES);
    partial_sum_kernel<<<128, 256, 0, stream>>>(deg, part);
    scan_part_kernel<<<1, 128, 0, stream>>>(part);
    off_kernel<<<128, 256, 0, stream>>>(deg, part, off);
    scatter_kernel<<<N_EDGES / 256, 256, 0, stream>>>(src, dst, off, cursor, csr, N_EDGES);

    // ---- prep ----
    prep_xpad_kernel<<<(N_NODES * 80) / 256, 256, 0, stream>>>(x, xb);
    prep_encw_kernel<<<256, KPAD, 0, stream>>>(syn_w, ant_w, wenc);
    prep_fusw_kernel<<<512, 256, 0, stream>>>(fusion_w, wfus);
    prep_combw_kernel<<<3072, 256, 0, stream>>>(Wskip, Wq, Wk, Wv, wcomb);
    prep_bias_kernel<<<25, 256, 0, stream>>>(syn_b, ant_b, bskip, bq, bk, bv, benc, bcomb);

    // ---- encoder ----
    mfma_gemm<1><<<dim3(N_NODES / 128, 2), 256, 0, stream>>>(
        xb, KPAD, wenc, benc, tenc, 256, KPAD);
    mfma_gemm256<256, 0, 0><<<256, 512, 0, stream>>>(
        tenc, 256, wfus, fusion_b, hA, D_FUSED, hA, D_FUSED, D_FUSED, nullptr, 2);

    // ---- transformer layers ----
    bf16* hcur = hA;
    bf16* hnew = hB;
    for (int l = 0; l < N_LAYERS; ++l) {
        mfma_gemm256<512, 0, 1><<<1024, 512, 0, stream>>>(
            hcur, D_FUSED, wcomb + (size_t)l * 2048 * D_FUSED,
            bcomb + (size_t)l * 2048,
            hnew, D_FUSED, nullptr, 0, 512, qkv, 8);
        attn_kernel<<<N_NODES, 256, 0, stream>>>(qkv, hnew, off, csr);
        bf16* tmp = hcur; hcur = hnew; hnew = tmp;
    }

    // ---- pool + classify ----
    pool_kernel<<<N_GRAPHS, 256, 0, stream>>>(hcur, batch, pooled);
    cls_kernel<<<N_GRAPHS, 128, 0, stream>>>(pooled, cls_w1, cls_b1, cls_w2, cls_b2,
                                             (float*)d_out);
}

// Round 20
// 562.602 us; speedup vs baseline: 4.3584x; 4.3584x over previous
//
#include <hip/hip_runtime.h>
#include <hip/hip_bf16.h>
#include <hip/hip_fp8.h>
#include <math.h>

#define N_NODES 32768
#define N_EDGES 262144
#define N_GRAPHS 512
#define IN_DIM 300
#define KPAD 320
#define HID 128
#define HEADS 4
#define D_FUSED 512
#define N_LAYERS 3

typedef __hip_bfloat16 bf16;
typedef short bf16x8 __attribute__((ext_vector_type(8)));
typedef short bf16x4 __attribute__((ext_vector_type(4)));
typedef float f32x4 __attribute__((ext_vector_type(4)));
typedef float f32x2 __attribute__((ext_vector_type(2)));

__device__ __forceinline__ float bfs_to_f(short s)
{
    unsigned u = ((unsigned)(unsigned short)s) << 16;
    return __builtin_bit_cast(float, u);
}

__device__ __forceinline__ short f_to_bfs(float v)
{
    return (short)__builtin_bit_cast(unsigned short, __float2bfloat16(v));
}

__device__ __forceinline__ void bf8_to_f32(bf16x8 v, float* f)
{
#pragma unroll
    for (int j = 0; j < 8; ++j) f[j] = bfs_to_f(v[j]);
}

__device__ __forceinline__ unsigned char f32_to_fp8(float v)
{
#if __has_builtin(__builtin_amdgcn_cvt_pk_fp8_f32)
    int p = __builtin_amdgcn_cvt_pk_fp8_f32(v, v, 0, false);
    return (unsigned char)(p & 0xff);
#else
    __hip_fp8_e4m3 t(v);
    return (unsigned char)t.__x;
#endif
}

__device__ __forceinline__ void fp8x8_to_f32(uint2 w, float* f)
{
#if __has_builtin(__builtin_amdgcn_cvt_pk_f32_fp8)
    f32x2 a = __builtin_amdgcn_cvt_pk_f32_fp8((int)w.x, false);
    f32x2 b = __builtin_amdgcn_cvt_pk_f32_fp8((int)w.x, true);
    f32x2 c = __builtin_amdgcn_cvt_pk_f32_fp8((int)w.y, false);
    f32x2 d = __builtin_amdgcn_cvt_pk_f32_fp8((int)w.y, true);
    f[0] = a.x; f[1] = a.y; f[2] = b.x; f[3] = b.y;
    f[4] = c.x; f[5] = c.y; f[6] = d.x; f[7] = d.y;
#else
    const unsigned char* p = (const unsigned char*)&w;
#pragma unroll
    for (int j = 0; j < 8; ++j) {
        __hip_fp8_e4m3 t;
        t.__x = (__hip_fp8_storage_t)p[j];
        f[j] = (float)t;
    }
#endif
}

__device__ __forceinline__ void gload_lds16(const void* g, void* l)
{
    __builtin_amdgcn_global_load_lds(
        (const __attribute__((address_space(1))) void*)g,
        (__attribute__((address_space(3))) void*)l, 16, 0, 0);
}

// ---------------------------------------------------------------------------
// 256x256-tile MFMA GEMM, BK=64, 512 thr = 8 waves (2M x 4N), counted-vmcnt
// double buffer, TWO barriers per K-tile (round-16 validated config —
// REVERT after r19's runtime-indexed-acc spill; rule #20: acc indices must
// be compile-time constants).
// EPI=0: col<csplit -> C0 (bf16, ldc0), else C1 (bf16, ldc1, col-csplit).
// EPI=1: bcol<512 -> C0 bf16 (ld ldc0); else -> C2 fp8 e4m3, ld 1536,
//        at col-512 (unified q|k|v fp8 buffer).
// Requires M%256==0, N%256==0, K%64==0, K>=128, 16B-aligned rows.
// ---------------------------------------------------------------------------
template <int K, int ACT, int EPI>
__global__ __launch_bounds__(512, 2) void mfma_gemm256(
    const bf16* __restrict__ A, int lda,
    const bf16* __restrict__ Bt,
    const float* __restrict__ bias,
    bf16* __restrict__ C0, int ldc0,
    bf16* __restrict__ C1, int ldc1, int csplit,
    unsigned char* __restrict__ C2,
    int nbx)
{
    __shared__ __align__(16) char lds[131072];
    // slab(buf, mat, half) = buf*65536 + mat*32768 + half*16384

    const int t = threadIdx.x;
    const int wid = t >> 6, lane = t & 63;
    const int hi = lane >> 4, li = lane & 15;
    const int wr = wid >> 2, wc = wid & 3;

    int wg = blockIdx.x;
    if ((gridDim.x & 7) == 0) {              // bijective XCD swizzle
        const int cpx = gridDim.x >> 3;
        wg = (wg & 7) * cpx + (wg >> 3);
    }
    const int mb = wg / nbx, nb = wg % nbx;
    const int brow = mb * 256, bcol = nb * 256;
    constexpr int NT = K >> 6;

    const int row0 = t >> 3, sl0 = (((t & 7) ^ (row0 & 7)) * 8);
    const int c1i = t + 512;
    const int row1 = c1i >> 3, sl1 = (((c1i & 7) ^ (row1 & 7)) * 8);

    // part q: 0 = A-half0, 1 = A-half1, 2 = B-half0, 3 = B-half1
    const bf16* srcs[4][2];
    srcs[0][0] = A  + (size_t)(brow + row0)       * lda + sl0;
    srcs[0][1] = A  + (size_t)(brow + row1)       * lda + sl1;
    srcs[1][0] = A  + (size_t)(brow + 128 + row0) * lda + sl0;
    srcs[1][1] = A  + (size_t)(brow + 128 + row1) * lda + sl1;
    srcs[2][0] = Bt + (size_t)(bcol + row0)       * K   + sl0;
    srcs[2][1] = Bt + (size_t)(bcol + row1)       * K   + sl1;
    srcs[3][0] = Bt + (size_t)(bcol + 128 + row0) * K   + sl0;
    srcs[3][1] = Bt + (size_t)(bcol + 128 + row1) * K   + sl1;

    auto stage_part = [&](int buf, int kt1, int q) {
        const int ko = kt1 * 64;
        const int slab = buf * 65536 + (q >> 1) * 32768 + (q & 1) * 16384;
        gload_lds16(srcs[q][0] + ko, lds + slab + wid * 1024);
        gload_lds16(srcs[q][1] + ko, lds + slab + 8192 + wid * 1024);
    };

    f32x4 acc[8][4] = {};

#pragma unroll
    for (int q = 0; q < 4; ++q) stage_part(0, 0, q);

#pragma unroll
    for (int kt = 0; kt < NT; ++kt) {
        const int b = kt & 1;
        const char* Aslab = lds + b * 65536 + wr * 16384;
        const char* Bslab = lds + b * 65536 + 32768 + (wc >> 1) * 16384;
        const int bRow0 = (wc & 1) * 64;

        // tile start: issue next tile's part 0, counted wait (this tile's 8
        // loads retired; 2 newest in flight), then ONE barrier.
        if (kt < NT - 1) {
            stage_part(b ^ 1, kt + 1, 0);
            asm volatile("s_waitcnt vmcnt(2)" ::: "memory");
        } else {
            asm volatile("s_waitcnt vmcnt(0)" ::: "memory");
        }
        __builtin_amdgcn_s_barrier();        // all waves' DMA for tile kt landed
        __builtin_amdgcn_sched_barrier(0);   // pin: no reads hoisted above

        bf16x8 bfrag[4][2];
#pragma unroll
        for (int n = 0; n < 4; ++n)
#pragma unroll
            for (int ks = 0; ks < 2; ++ks) {
                const int row = bRow0 + n * 16 + li;
                bfrag[n][ks] = *(const bf16x8*)(
                    Bslab + row * 128 + (((ks * 4 + hi) ^ (row & 7)) << 4));
            }

        // 4 MFMA quadrants, NO intermediate barriers: per-wave lgkmcnt orders
        // each wave's reads vs its MFMAs; waves slip and overlap freely.
#pragma unroll
        for (int q = 0; q < 4; ++q) {
            if (q > 0 && kt < NT - 1) stage_part(b ^ 1, kt + 1, q);
            bf16x8 af[2][2];
#pragma unroll
            for (int mm = 0; mm < 2; ++mm)
#pragma unroll
                for (int ks = 0; ks < 2; ++ks) {
                    const int row = (q * 2 + mm) * 16 + li;
                    af[mm][ks] = *(const bf16x8*)(
                        Aslab + row * 128 + (((ks * 4 + hi) ^ (row & 7)) << 4));
                }
            __builtin_amdgcn_s_setprio(1);
#pragma unroll
            for (int ks = 0; ks < 2; ++ks)
#pragma unroll
                for (int mm = 0; mm < 2; ++mm)
#pragma unroll
                    for (int n = 0; n < 4; ++n)
                        acc[q * 2 + mm][n] = __builtin_amdgcn_mfma_f32_16x16x32_bf16(
                            af[mm][ks], bfrag[n][ks], acc[q * 2 + mm][n], 0, 0, 0);
            __builtin_amdgcn_s_setprio(0);
        }

        // tile end: buf b fully consumed before tile kt+1 stages kt+2 into it
        __builtin_amdgcn_s_barrier();
        __builtin_amdgcn_sched_barrier(0);   // pin: next tile's stores stay below
    }

    // epilogue: C/D layout col=li, row=hi*4+r; destination block-uniform
    if (EPI == 0) {
        const bool lo = (bcol < csplit);
        bf16* Cd = lo ? C0 : C1;
        const int ldc = lo ? ldc0 : ldc1;
        const int csub = lo ? 0 : csplit;
#pragma unroll
        for (int m = 0; m < 8; ++m)
#pragma unroll
            for (int n = 0; n < 4; ++n) {
                const int col = bcol + wc * 64 + n * 16 + li;
                const float bv = bias[col];
#pragma unroll
                for (int r = 0; r < 4; ++r) {
                    const int row = brow + wr * 128 + m * 16 + hi * 4 + r;
                    float v = acc[m][n][r] + bv;
                    if (ACT == 1) v = fmaxf(v, 0.f);
                    Cd[(size_t)row * ldc + (col - csub)] = __float2bfloat16(v);
                }
            }
    } else if (bcol < 512) {
#pragma unroll
        for (int m = 0; m < 8; ++m)
#pragma unroll
            for (int n = 0; n < 4; ++n) {
                const int col = bcol + wc * 64 + n * 16 + li;
                const float bv = bias[col];
#pragma unroll
                for (int r = 0; r < 4; ++r) {
                    const int row = brow + wr * 128 + m * 16 + hi * 4 + r;
                    C0[(size_t)row * ldc0 + col] = __float2bfloat16(acc[m][n][r] + bv);
                }
            }
    } else {
        // fp8 q|k|v unified buffer, ld 1536, at col-512
#pragma unroll
        for (int m = 0; m < 8; ++m)
#pragma unroll
            for (int n = 0; n < 4; ++n) {
                const int col = bcol + wc * 64 + n * 16 + li;
                const float bv = bias[col];
#pragma unroll
                for (int r = 0; r < 4; ++r) {
                    const int row = brow + wr * 128 + m * 16 + hi * 4 + r;
                    C2[(size_t)row * 1536 + (col - 512)] = f32_to_fp8(acc[m][n][r] + bv);
                }
            }
    }
}

// ---------------------------------------------------------------------------
// 128x128 MFMA GEMM (m97 structure) — kept for the small-N encoder GEMM.
// ---------------------------------------------------------------------------
template <int ACT>
__global__ __launch_bounds__(256) void mfma_gemm(
    const bf16* __restrict__ A, int lda,
    const bf16* __restrict__ Bt,
    const float* __restrict__ bias,
    bf16* __restrict__ C, int ldc, int K)
{
    __shared__ __align__(16) char lds[16384];
    char* As = lds;
    char* Bs = lds + 8192;

    const int t = threadIdx.x;
    const int wid = t >> 6, lane = t & 63;
    const int brow = blockIdx.x * 128;
    const int bcol = blockIdx.y * 128;
    const int wr = wid >> 1, wc = wid & 1;

    f32x4 acc[4][4] = {};

    for (int k0 = 0; k0 < K; k0 += 32) {
#pragma unroll
        for (int j = 0; j < 2; ++j) {
            const int seg = wid * 2 + j;
            const int row = seg * 16 + (lane >> 2);
            const int clin = lane & 3;
            const int clog = clin ^ ((row >> 1) & 3);
            gload_lds16(A + (size_t)(brow + row) * lda + k0 + clog * 8,
                        As + seg * 1024);
            gload_lds16(Bt + (size_t)(bcol + row) * K + k0 + clog * 8,
                        Bs + seg * 1024);
        }
        __syncthreads();

        bf16x8 af[4], bfr[4];
#pragma unroll
        for (int m = 0; m < 4; ++m) {
            const int row = wr * 64 + m * 16 + (lane & 15);
            const int cl = (lane >> 4) ^ ((row >> 1) & 3);
            af[m] = *(const bf16x8*)(As + row * 64 + cl * 16);
        }
#pragma unroll
        for (int n = 0; n < 4; ++n) {
            const int row = wc * 64 + n * 16 + (lane & 15);
            const int cl = (lane >> 4) ^ ((row >> 1) & 3);
            bfr[n] = *(const bf16x8*)(Bs + row * 64 + cl * 16);
        }
#pragma unroll
        for (int m = 0; m < 4; ++m)
#pragma unroll
            for (int n = 0; n < 4; ++n)
                acc[m][n] = __builtin_amdgcn_mfma_f32_16x16x32_bf16(
                    af[m], bfr[n], acc[m][n], 0, 0, 0);
        __syncthreads();
    }

#pragma unroll
    for (int m = 0; m < 4; ++m) {
#pragma unroll
        for (int n = 0; n < 4; ++n) {
            const int col = bcol + wc * 64 + n * 16 + (lane & 15);
            const float bv = bias[col];
#pragma unroll
            for (int r = 0; r < 4; ++r) {
                const int row = brow + wr * 64 + m * 16 + (lane >> 4) * 4 + r;
                float v = acc[m][n][r] + bv;
                if (ACT == 1) v = fmaxf(v, 0.f);
                C[(size_t)row * ldc + col] = __float2bfloat16(v);
            }
        }
    }
}

// ---------------------------------------------------------------------------
// Weight/input prep
// ---------------------------------------------------------------------------
// Vectorized pad+cast: 300 = 75 float4 exactly; quads 75..79 are zero pad.
__global__ void prep_xpad_kernel(const float* __restrict__ x, bf16* __restrict__ xb)
{
    const int idx = blockIdx.x * 256 + threadIdx.x;   // grid covers N*80 exactly
    const int n = idx / 80, q = idx % 80;
    bf16x4 o;
    if (q < 75) {
        const float4 v = *(const float4*)(x + (size_t)n * IN_DIM + q * 4);
        o[0] = f_to_bfs(v.x); o[1] = f_to_bfs(v.y);
        o[2] = f_to_bfs(v.z); o[3] = f_to_bfs(v.w);
    } else {
        o[0] = 0; o[1] = 0; o[2] = 0; o[3] = 0;
    }
    *(bf16x4*)(xb + (size_t)n * KPAD + q * 4) = o;
}

__global__ void prep_encw_kernel(const float* __restrict__ syn_w,
                                 const float* __restrict__ ant_w,
                                 bf16* __restrict__ wt)
{
    const int c = blockIdx.x, k = threadIdx.x;
    float v = 0.f;
    if (k < IN_DIM) v = (c < HID) ? syn_w[k * HID + c] : ant_w[k * HID + (c - HID)];
    wt[c * KPAD + k] = __float2bfloat16(v);
}

__global__ void prep_fusw_kernel(const float* __restrict__ fw, bf16* __restrict__ wt)
{
    const int c = blockIdx.x, k = threadIdx.x;
    wt[c * 256 + k] = __float2bfloat16(fw[k * D_FUSED + c]);
}

__global__ __launch_bounds__(256) void prep_combw_kernel(
    const float* __restrict__ Wskip,
    const float* __restrict__ Wq,
    const float* __restrict__ Wk,
    const float* __restrict__ Wv,
    bf16* __restrict__ wt)
{
    __shared__ float tile[32][33];
    const int blk = blockIdx.x;
    const int l = blk >> 10, rem = blk & 1023;   // 64*16 = 1024 per layer
    const int cb = rem >> 4, kb = rem & 15;
    const int c0 = cb * 32;

    const int sel = c0 >> 9;
    const float* mat = (sel == 0) ? Wskip : (sel == 1) ? Wq : (sel == 2) ? Wk : Wv;
    const int cp0 = c0 & 511;

    const int j = threadIdx.x & 31;    // fast dim
    const int i0 = threadIdx.x >> 5;   // 0..7
#pragma unroll
    for (int s = 0; s < 4; ++s) {
        const int i = i0 + 8 * s;      // k within tile
        tile[i][j] = mat[((size_t)l * 512 + kb * 32 + i) * 512 + cp0 + j];
    }
    __syncthreads();
#pragma unroll
    for (int s = 0; s < 4; ++s) {
        const int jj = i0 + 8 * s;     // c within tile
        wt[((size_t)l * 2048 + c0 + jj) * 512 + kb * 32 + j] =
            __float2bfloat16(tile[j][jj]);
    }
}

__global__ void prep_bias_kernel(const float* __restrict__ syn_b,
                                 const float* __restrict__ ant_b,
                                 const float* __restrict__ bskip,
                                 const float* __restrict__ bq,
                                 const float* __restrict__ bk,
                                 const float* __restrict__ bv,
                                 float* __restrict__ benc,
                                 float* __restrict__ bcomb)
{
    const int i = blockIdx.x * 256 + threadIdx.x;
    if (i < 256) benc[i] = (i < HID) ? syn_b[i] : ant_b[i - HID];
    const int j = i - 256;
    if (j >= 0 && j < 6144) {
        const int l = j >> 11, c = j & 2047;
        const int sel = c >> 9, col = c & 511;
        const float* s = (sel == 0) ? bskip : (sel == 1) ? bq : (sel == 2) ? bk : bv;
        bcomb[j] = s[l * D_FUSED + col];
    }
}

// ---------------------------------------------------------------------------
// CSR build
// ---------------------------------------------------------------------------
__global__ void zero_int_kernel(int* __restrict__ p, int n)
{
    int i = blockIdx.x * 256 + threadIdx.x;
    if (i < n) p[i] = 0;
}

__global__ void hist_kernel(const int* __restrict__ dst, int* __restrict__ deg, int E)
{
    int e = blockIdx.x * 256 + threadIdx.x;
    if (e < E) atomicAdd(&deg[dst[e]], 1);
}

__global__ __launch_bounds__(256) void partial_sum_kernel(const int* __restrict__ deg,
                                                          int* __restrict__ part)
{
    int v = deg[blockIdx.x * 256 + threadIdx.x];
#pragma unroll
    for (int o = 32; o; o >>= 1) v += __shfl_xor(v, o);
    __shared__ int w4[4];
    if ((threadIdx.x & 63) == 0) w4[threadIdx.x >> 6] = v;
    __syncthreads();
    if (threadIdx.x == 0) part[blockIdx.x] = w4[0] + w4[1] + w4[2] + w4[3];
}

__global__ __launch_bounds__(128) void scan_part_kernel(int* __restrict__ part)
{
    __shared__ int s[128];
    const int t = threadIdx.x;
    s[t] = part[t];
    __syncthreads();
    for (int o = 1; o < 128; o <<= 1) {
        int v = (t >= o) ? s[t - o] : 0;
        __syncthreads();
        s[t] += v;
        __syncthreads();
    }
    part[t] = (t == 0) ? 0 : s[t - 1];  // exclusive
}

__global__ __launch_bounds__(256) void off_kernel(const int* __restrict__ deg,
                                                  const int* __restrict__ part,
                                                  int* __restrict__ off)
{
    __shared__ int s[256];
    const int b = blockIdx.x, t = threadIdx.x;
    s[t] = deg[b * 256 + t];
    __syncthreads();
    for (int o = 1; o < 256; o <<= 1) {
        int v = (t >= o) ? s[t - o] : 0;
        __syncthreads();
        s[t] += v;
        __syncthreads();
    }
    const int excl = (t == 0) ? 0 : s[t - 1];
    off[b * 256 + t] = part[b] + excl;
    if (b == 127 && t == 255) off[N_NODES] = part[127] + s[255];
}

__global__ void scatter_kernel(const int* __restrict__ src, const int* __restrict__ dst,
                               const int* __restrict__ off, int* __restrict__ cursor,
                               int* __restrict__ csr_src, int E)
{
    int e = blockIdx.x * 256 + threadIdx.x;
    if (e < E) {
        int d = dst[e];
        int pos = atomicAdd(&cursor[d], 1);
        csr_src[off[d] + pos] = src[e];
    }
}

// ---------------------------------------------------------------------------
// 8-edge/iteration attention as TWO independent 4-edge sets; no online max
// (shift-invariant, logits bounded << 1). All of q,k,v fp8 in one
// [N][1536] buffer: q at +0, k at +512, v at +1024 (each hd*128+dim).
// Block = 256 = 4 waves; wave = head hd of node blockIdx.x.
// Wave = 4 groups x 16 lanes; group g handles edges e0+g (set A) and
// e0+4+g (set B). Lane sub holds head dims sub*8..sub*8+7.
// hout holds skip projection; add attention, relu, write back.
// ---------------------------------------------------------------------------
__global__ __launch_bounds__(256) void attn_kernel(
    const unsigned char* __restrict__ qkvb, bf16* __restrict__ hout,
    const int* __restrict__ off, const int* __restrict__ csr)
{
    const int n = blockIdx.x;
    const int hd = threadIdx.x >> 6;
    const int lane = threadIdx.x & 63;
    const int g = lane >> 4, sub = lane & 15;
    const float scale = 0.08838834764831845f;  // 1/sqrt(128)

    float qf[8];
    fp8x8_to_f32(*(const uint2*)(qkvb + (size_t)n * 1536 + hd * 128 + sub * 8), qf);

    float zA = 0.f, zB = 0.f;
    float accA[8] = {}, accB[8] = {};

    const int s0 = off[n], s1 = off[n + 1];
    for (int e0 = s0; e0 < s1; e0 += 8) {
        const int ea = e0 + g;
        const int eb = e0 + 4 + g;
        const bool va = (ea < s1);
        const bool vb = (eb < s1);
        const int sa = va ? csr[ea] : 0;
        const int sb = vb ? csr[eb] : 0;
        const unsigned char* pa = qkvb + (size_t)sa * 1536 + hd * 128 + sub * 8;
        const unsigned char* pb = qkvb + (size_t)sb * 1536 + hd * 128 + sub * 8;

        // issue all 4 loads up front (16 gathers in flight across the wave)
        const uint2 kwa = *(const uint2*)(pa + 512);
        const uint2 kwb = *(const uint2*)(pb + 512);
        const uint2 vwa = *(const uint2*)(pa + 1024);
        const uint2 vwb = *(const uint2*)(pb + 1024);

        float kfa[8], kfb[8];
        fp8x8_to_f32(kwa, kfa);
        fp8x8_to_f32(kwb, kfb);
        float da = 0.f, db = 0.f;
#pragma unroll
        for (int j = 0; j < 8; ++j) {
            da = fmaf(qf[j], kfa[j], da);
            db = fmaf(qf[j], kfb[j], db);
        }
        // two independent shuffle chains, interleaved
        da += __shfl_xor(da, 1);  db += __shfl_xor(db, 1);
        da += __shfl_xor(da, 2);  db += __shfl_xor(db, 2);
        da += __shfl_xor(da, 4);  db += __shfl_xor(db, 4);
        da += __shfl_xor(da, 8);  db += __shfl_xor(db, 8);

        const float wa = va ? __expf(da * scale) : 0.f;
        const float wb = vb ? __expf(db * scale) : 0.f;
        zA += wa;
        zB += wb;

        float vfa[8], vfb[8];
        fp8x8_to_f32(vwa, vfa);
        fp8x8_to_f32(vwb, vfb);
#pragma unroll
        for (int j = 0; j < 8; ++j) {
            accA[j] = fmaf(wa, vfa[j], accA[j]);
            accB[j] = fmaf(wb, vfb[j], accB[j]);
        }
    }

    // set merge: plain register adds (free), then the 4-group merge
    float zz = zA + zB;
    zz += __shfl_xor(zz, 16);
    zz += __shfl_xor(zz, 32);
    const float inv = 1.f / (zz + 1e-16f);

    float o[8];
#pragma unroll
    for (int j = 0; j < 8; ++j) {
        float a = accA[j] + accB[j];
        a += __shfl_xor(a, 16);
        a += __shfl_xor(a, 32);
        o[j] = a * inv;
    }

    if (g == 0) {
        const size_t ob = (size_t)n * D_FUSED + hd * HID + sub * 8;
        const bf16x8 sk = *(const bf16x8*)(hout + ob);
        bf16x8 res;
#pragma unroll
        for (int j = 0; j < 8; ++j)
            res[j] = f_to_bfs(fmaxf(o[j] + bfs_to_f(sk[j]), 0.f));
        *(bf16x8*)(hout + ob) = res;
    }
}

// ---------------------------------------------------------------------------
// Mean-pool, vectorized: 4 node-lanes (waves) x 64 dim-lanes x bf16x8.
// ---------------------------------------------------------------------------
__global__ __launch_bounds__(256) void pool_kernel(const bf16* __restrict__ h,
                                                   const int* __restrict__ batch,
                                                   float* __restrict__ pooled)
{
    const int g = blockIdx.x;
    int a = 0, b = N_NODES;
    while (a < b) { int mid = (a + b) >> 1; if (batch[mid] < g) a = mid + 1; else b = mid; }
    const int start = a;
    b = N_NODES;
    while (a < b) { int mid = (a + b) >> 1; if (batch[mid] < g + 1) a = mid + 1; else b = mid; }
    const int end = a;
    const float invc = 1.f / fmaxf((float)(end - start), 1.f);

    const int nl = threadIdx.x >> 6;   // node lane (wave)
    const int dl = threadIdx.x & 63;   // dim lane: dims dl*8..dl*8+7

    float s[8] = {};
    for (int nidx = start + nl; nidx < end; nidx += 4) {
        const bf16x8 v = *(const bf16x8*)(h + (size_t)nidx * D_FUSED + dl * 8);
#pragma unroll
        for (int j = 0; j < 8; ++j) s[j] += bfs_to_f(v[j]);
    }

    __shared__ float red[4][512];
#pragma unroll
    for (int j = 0; j < 8; ++j) red[nl][dl * 8 + j] = s[j];
    __syncthreads();
    if (nl == 0) {
#pragma unroll
        for (int j = 0; j < 8; ++j) {
            const int d = dl * 8 + j;
            pooled[(size_t)g * D_FUSED + d] =
                (red[0][d] + red[1][d] + red[2][d] + red[3][d]) * invc;
        }
    }
}

__global__ __launch_bounds__(128) void cls_kernel(const float* __restrict__ pooled,
                                                  const float* __restrict__ w1,
                                                  const float* __restrict__ b1,
                                                  const float* __restrict__ w2,
                                                  const float* __restrict__ b2,
                                                  float* __restrict__ out)
{
    const int g = blockIdx.x;
    const int j = threadIdx.x;
    const float* p = pooled + (size_t)g * D_FUSED;
    float acc = 0.f;
    for (int i = 0; i < D_FUSED; ++i) acc += p[i] * w1[i * HID + j];
    const float hid = fmaxf(acc + b1[j], 0.f);
    float val = hid * w2[j];
#pragma unroll
    for (int o = 32; o; o >>= 1) val += __shfl_xor(val, o);
    __shared__ float ws2[2];
    if ((threadIdx.x & 63) == 0) ws2[threadIdx.x >> 6] = val;
    __syncthreads();
    if (threadIdx.x == 0) {
        const float sum = ws2[0] + ws2[1] + b2[0];
        out[g] = 1.f / (1.f + __expf(-sum));
    }
}

// ---------------------------------------------------------------------------
extern "C" void kernel_launch(void* const* d_in, const int* in_sizes, int n_in,
                              void* d_out, int out_size, void* d_ws, size_t ws_size,
                              hipStream_t stream)
{
    const float* x        = (const float*)d_in[0];
    const int*   ei       = (const int*)d_in[1];
    const int*   batch    = (const int*)d_in[2];
    const float* syn_w    = (const float*)d_in[3];
    const float* syn_b    = (const float*)d_in[4];
    const float* ant_w    = (const float*)d_in[5];
    const float* ant_b    = (const float*)d_in[6];
    const float* fusion_w = (const float*)d_in[7];
    const float* fusion_b = (const float*)d_in[8];
    const float* Wq       = (const float*)d_in[9];
    const float* bq       = (const float*)d_in[10];
    const float* Wk       = (const float*)d_in[11];
    const float* bk       = (const float*)d_in[12];
    const float* Wv       = (const float*)d_in[13];
    const float* bv       = (const float*)d_in[14];
    const float* Wskip    = (const float*)d_in[15];
    const float* bskip    = (const float*)d_in[16];
    const float* cls_w1   = (const float*)d_in[17];
    const float* cls_b1   = (const float*)d_in[18];
    const float* cls_w2   = (const float*)d_in[19];
    const float* cls_b2   = (const float*)d_in[20];

    const int* src = ei;
    const int* dst = ei + N_EDGES;

    // ---- workspace layout (~125 MB) ----
    const size_t NV = (size_t)N_NODES * D_FUSED;
    bf16* hA    = (bf16*)d_ws;                         // N*512 bf16
    bf16* hB    = hA + NV;                             // N*512 bf16
    unsigned char* qkv = (unsigned char*)(hB + NV);    // N*1536 fp8 (q|k|v)
    bf16* wenc  = (bf16*)(qkv + (size_t)N_NODES * 1536);     // 256*320
    bf16* wfus  = wenc + 256 * KPAD;                   // 512*256
    bf16* wcomb = wfus + 512 * 256;                    // 3*2048*512
    float* benc = (float*)(wcomb + (size_t)3 * 2048 * 512);  // 256
    float* bcomb = benc + 256;                         // 6144
    float* pooled = bcomb + 6144;                      // G*512
    int* deg    = (int*)(pooled + (size_t)N_GRAPHS * D_FUSED);
    int* cursor = deg + N_NODES;
    int* part   = cursor + N_NODES;                    // 128
    int* off    = part + 128;                          // N+1
    int* csr    = off + N_NODES + 1;                   // E

    bf16* xb   = (bf16*)qkv;  // N*320 bf16 (40MB < 48MB), dead before layer GEMMs
    bf16* tenc = hB;          // N*256, dead before first layer GEMM

    // ---- CSR build ----
    zero_int_kernel<<<(2 * N_NODES + 255) / 256, 256, 0, stream>>>(deg, 2 * N_NODES);
    hist_kernel<<<N_EDGES / 256, 256, 0, stream>>>(dst, deg, N_EDGES);
    partial_sum_kernel<<<128, 256, 0, stream>>>(deg, part);
    scan_part_kernel<<<1, 128, 0, stream>>>(part);
    off_kernel<<<128, 256, 0, stream>>>(deg, part, off);
    scatter_kernel<<<N_EDGES / 256, 256, 0, stream>>>(src, dst, off, cursor, csr, N_EDGES);

    // ---- prep ----
    prep_xpad_kernel<<<(N_NODES * 80) / 256, 256, 0, stream>>>(x, xb);
    prep_encw_kernel<<<256, KPAD, 0, stream>>>(syn_w, ant_w, wenc);
    prep_fusw_kernel<<<512, 256, 0, stream>>>(fusion_w, wfus);
    prep_combw_kernel<<<3072, 256, 0, stream>>>(Wskip, Wq, Wk, Wv, wcomb);
    prep_bias_kernel<<<25, 256, 0, stream>>>(syn_b, ant_b, bskip, bq, bk, bv, benc, bcomb);

    // ---- encoder ----
    mfma_gemm<1><<<dim3(N_NODES / 128, 2), 256, 0, stream>>>(
        xb, KPAD, wenc, benc, tenc, 256, KPAD);
    mfma_gemm256<256, 0, 0><<<256, 512, 0, stream>>>(
        tenc, 256, wfus, fusion_b, hA, D_FUSED, hA, D_FUSED, D_FUSED, nullptr, 2);

    // ---- transformer layers ----
    bf16* hcur = hA;
    bf16* hnew = hB;
    for (int l = 0; l < N_LAYERS; ++l) {
        mfma_gemm256<512, 0, 1><<<1024, 512, 0, stream>>>(
            hcur, D_FUSED, wcomb + (size_t)l * 2048 * D_FUSED,
            bcomb + (size_t)l * 2048,
            hnew, D_FUSED, nullptr, 0, 512, qkv, 8);
        attn_kernel<<<N_NODES, 256, 0, stream>>>(qkv, hnew, off, csr);
        bf16* tmp = hcur; hcur = hnew; hnew = tmp;
    }

    // ---- pool + classify ----
    pool_kernel<<<N_GRAPHS, 256, 0, stream>>>(hcur, batch, pooled);
    cls_kernel<<<N_GRAPHS, 128, 0, stream>>>(pooled, cls_w1, cls_b1, cls_w2, cls_b2,
                                             (float*)d_out);
}

// Round 21
// 559.073 us; speedup vs baseline: 4.3860x; 1.0063x over previous
//
#include <hip/hip_runtime.h>
#include <hip/hip_bf16.h>
#include <hip/hip_fp8.h>
#include <math.h>

#define N_NODES 32768
#define N_EDGES 262144
#define N_GRAPHS 512
#define IN_DIM 300
#define KPAD 320
#define HID 128
#define HEADS 4
#define D_FUSED 512
#define N_LAYERS 3

typedef __hip_bfloat16 bf16;
typedef short bf16x8 __attribute__((ext_vector_type(8)));
typedef short bf16x4 __attribute__((ext_vector_type(4)));
typedef float f32x4 __attribute__((ext_vector_type(4)));
typedef float f32x2 __attribute__((ext_vector_type(2)));

__device__ __forceinline__ float bfs_to_f(short s)
{
    unsigned u = ((unsigned)(unsigned short)s) << 16;
    return __builtin_bit_cast(float, u);
}

__device__ __forceinline__ short f_to_bfs(float v)
{
    return (short)__builtin_bit_cast(unsigned short, __float2bfloat16(v));
}

__device__ __forceinline__ void bf8_to_f32(bf16x8 v, float* f)
{
#pragma unroll
    for (int j = 0; j < 8; ++j) f[j] = bfs_to_f(v[j]);
}

__device__ __forceinline__ unsigned char f32_to_fp8(float v)
{
#if __has_builtin(__builtin_amdgcn_cvt_pk_fp8_f32)
    int p = __builtin_amdgcn_cvt_pk_fp8_f32(v, v, 0, false);
    return (unsigned char)(p & 0xff);
#else
    __hip_fp8_e4m3 t(v);
    return (unsigned char)t.__x;
#endif
}

__device__ __forceinline__ void fp8x8_to_f32(uint2 w, float* f)
{
#if __has_builtin(__builtin_amdgcn_cvt_pk_f32_fp8)
    f32x2 a = __builtin_amdgcn_cvt_pk_f32_fp8((int)w.x, false);
    f32x2 b = __builtin_amdgcn_cvt_pk_f32_fp8((int)w.x, true);
    f32x2 c = __builtin_amdgcn_cvt_pk_f32_fp8((int)w.y, false);
    f32x2 d = __builtin_amdgcn_cvt_pk_f32_fp8((int)w.y, true);
    f[0] = a.x; f[1] = a.y; f[2] = b.x; f[3] = b.y;
    f[4] = c.x; f[5] = c.y; f[6] = d.x; f[7] = d.y;
#else
    const unsigned char* p = (const unsigned char*)&w;
#pragma unroll
    for (int j = 0; j < 8; ++j) {
        __hip_fp8_e4m3 t;
        t.__x = (__hip_fp8_storage_t)p[j];
        f[j] = (float)t;
    }
#endif
}

__device__ __forceinline__ void gload_lds16(const void* g, void* l)
{
    __builtin_amdgcn_global_load_lds(
        (const __attribute__((address_space(1))) void*)g,
        (__attribute__((address_space(3))) void*)l, 16, 0, 0);
}

// ---------------------------------------------------------------------------
// 256x256-tile MFMA GEMM, BK=64, 512 thr = 8 waves (2M x 4N), counted-vmcnt
// double buffer, TWO barriers per K-tile (round-16/20 validated config).
// EPI=0: col<csplit -> C0 (bf16, ldc0), else C1 (bf16, ldc1, col-csplit).
// EPI=1: bcol<512 -> C0 bf16 (ld ldc0); else -> C2 fp8 e4m3, ld 1536,
//        at col-512 (unified q|k|v fp8 buffer).
// Requires M%256==0, N%256==0, K%64==0, K>=128, 16B-aligned rows.
// ---------------------------------------------------------------------------
template <int K, int ACT, int EPI>
__global__ __launch_bounds__(512, 2) void mfma_gemm256(
    const bf16* __restrict__ A, int lda,
    const bf16* __restrict__ Bt,
    const float* __restrict__ bias,
    bf16* __restrict__ C0, int ldc0,
    bf16* __restrict__ C1, int ldc1, int csplit,
    unsigned char* __restrict__ C2,
    int nbx)
{
    __shared__ __align__(16) char lds[131072];
    // slab(buf, mat, half) = buf*65536 + mat*32768 + half*16384

    const int t = threadIdx.x;
    const int wid = t >> 6, lane = t & 63;
    const int hi = lane >> 4, li = lane & 15;
    const int wr = wid >> 2, wc = wid & 3;

    int wg = blockIdx.x;
    if ((gridDim.x & 7) == 0) {              // bijective XCD swizzle
        const int cpx = gridDim.x >> 3;
        wg = (wg & 7) * cpx + (wg >> 3);
    }
    const int mb = wg / nbx, nb = wg % nbx;
    const int brow = mb * 256, bcol = nb * 256;
    constexpr int NT = K >> 6;

    const int row0 = t >> 3, sl0 = (((t & 7) ^ (row0 & 7)) * 8);
    const int c1i = t + 512;
    const int row1 = c1i >> 3, sl1 = (((c1i & 7) ^ (row1 & 7)) * 8);

    // part q: 0 = A-half0, 1 = A-half1, 2 = B-half0, 3 = B-half1
    const bf16* srcs[4][2];
    srcs[0][0] = A  + (size_t)(brow + row0)       * lda + sl0;
    srcs[0][1] = A  + (size_t)(brow + row1)       * lda + sl1;
    srcs[1][0] = A  + (size_t)(brow + 128 + row0) * lda + sl0;
    srcs[1][1] = A  + (size_t)(brow + 128 + row1) * lda + sl1;
    srcs[2][0] = Bt + (size_t)(bcol + row0)       * K   + sl0;
    srcs[2][1] = Bt + (size_t)(bcol + row1)       * K   + sl1;
    srcs[3][0] = Bt + (size_t)(bcol + 128 + row0) * K   + sl0;
    srcs[3][1] = Bt + (size_t)(bcol + 128 + row1) * K   + sl1;

    auto stage_part = [&](int buf, int kt1, int q) {
        const int ko = kt1 * 64;
        const int slab = buf * 65536 + (q >> 1) * 32768 + (q & 1) * 16384;
        gload_lds16(srcs[q][0] + ko, lds + slab + wid * 1024);
        gload_lds16(srcs[q][1] + ko, lds + slab + 8192 + wid * 1024);
    };

    f32x4 acc[8][4] = {};

#pragma unroll
    for (int q = 0; q < 4; ++q) stage_part(0, 0, q);

#pragma unroll
    for (int kt = 0; kt < NT; ++kt) {
        const int b = kt & 1;
        const char* Aslab = lds + b * 65536 + wr * 16384;
        const char* Bslab = lds + b * 65536 + 32768 + (wc >> 1) * 16384;
        const int bRow0 = (wc & 1) * 64;

        // tile start: issue next tile's part 0, counted wait (this tile's 8
        // loads retired; 2 newest in flight), then ONE barrier.
        if (kt < NT - 1) {
            stage_part(b ^ 1, kt + 1, 0);
            asm volatile("s_waitcnt vmcnt(2)" ::: "memory");
        } else {
            asm volatile("s_waitcnt vmcnt(0)" ::: "memory");
        }
        __builtin_amdgcn_s_barrier();        // all waves' DMA for tile kt landed
        __builtin_amdgcn_sched_barrier(0);   // pin: no reads hoisted above

        bf16x8 bfrag[4][2];
#pragma unroll
        for (int n = 0; n < 4; ++n)
#pragma unroll
            for (int ks = 0; ks < 2; ++ks) {
                const int row = bRow0 + n * 16 + li;
                bfrag[n][ks] = *(const bf16x8*)(
                    Bslab + row * 128 + (((ks * 4 + hi) ^ (row & 7)) << 4));
            }

        // 4 MFMA quadrants, NO intermediate barriers: per-wave lgkmcnt orders
        // each wave's reads vs its MFMAs; waves slip and overlap freely.
#pragma unroll
        for (int q = 0; q < 4; ++q) {
            if (q > 0 && kt < NT - 1) stage_part(b ^ 1, kt + 1, q);
            bf16x8 af[2][2];
#pragma unroll
            for (int mm = 0; mm < 2; ++mm)
#pragma unroll
                for (int ks = 0; ks < 2; ++ks) {
                    const int row = (q * 2 + mm) * 16 + li;
                    af[mm][ks] = *(const bf16x8*)(
                        Aslab + row * 128 + (((ks * 4 + hi) ^ (row & 7)) << 4));
                }
            __builtin_amdgcn_s_setprio(1);
#pragma unroll
            for (int ks = 0; ks < 2; ++ks)
#pragma unroll
                for (int mm = 0; mm < 2; ++mm)
#pragma unroll
                    for (int n = 0; n < 4; ++n)
                        acc[q * 2 + mm][n] = __builtin_amdgcn_mfma_f32_16x16x32_bf16(
                            af[mm][ks], bfrag[n][ks], acc[q * 2 + mm][n], 0, 0, 0);
            __builtin_amdgcn_s_setprio(0);
        }

        // tile end: buf b fully consumed before tile kt+1 stages kt+2 into it
        __builtin_amdgcn_s_barrier();
        __builtin_amdgcn_sched_barrier(0);   // pin: next tile's stores stay below
    }

    // epilogue: C/D layout col=li, row=hi*4+r; destination block-uniform
    if (EPI == 0) {
        const bool lo = (bcol < csplit);
        bf16* Cd = lo ? C0 : C1;
        const int ldc = lo ? ldc0 : ldc1;
        const int csub = lo ? 0 : csplit;
#pragma unroll
        for (int m = 0; m < 8; ++m)
#pragma unroll
            for (int n = 0; n < 4; ++n) {
                const int col = bcol + wc * 64 + n * 16 + li;
                const float bv = bias[col];
#pragma unroll
                for (int r = 0; r < 4; ++r) {
                    const int row = brow + wr * 128 + m * 16 + hi * 4 + r;
                    float v = acc[m][n][r] + bv;
                    if (ACT == 1) v = fmaxf(v, 0.f);
                    Cd[(size_t)row * ldc + (col - csub)] = __float2bfloat16(v);
                }
            }
    } else if (bcol < 512) {
#pragma unroll
        for (int m = 0; m < 8; ++m)
#pragma unroll
            for (int n = 0; n < 4; ++n) {
                const int col = bcol + wc * 64 + n * 16 + li;
                const float bv = bias[col];
#pragma unroll
                for (int r = 0; r < 4; ++r) {
                    const int row = brow + wr * 128 + m * 16 + hi * 4 + r;
                    C0[(size_t)row * ldc0 + col] = __float2bfloat16(acc[m][n][r] + bv);
                }
            }
    } else {
        // fp8 q|k|v unified buffer, ld 1536, at col-512
#pragma unroll
        for (int m = 0; m < 8; ++m)
#pragma unroll
            for (int n = 0; n < 4; ++n) {
                const int col = bcol + wc * 64 + n * 16 + li;
                const float bv = bias[col];
#pragma unroll
                for (int r = 0; r < 4; ++r) {
                    const int row = brow + wr * 128 + m * 16 + hi * 4 + r;
                    C2[(size_t)row * 1536 + (col - 512)] = f32_to_fp8(acc[m][n][r] + bv);
                }
            }
    }
}

// ---------------------------------------------------------------------------
// 128x128 MFMA GEMM (m97 structure) — kept for the small-N encoder GEMM.
// ---------------------------------------------------------------------------
template <int ACT>
__global__ __launch_bounds__(256) void mfma_gemm(
    const bf16* __restrict__ A, int lda,
    const bf16* __restrict__ Bt,
    const float* __restrict__ bias,
    bf16* __restrict__ C, int ldc, int K)
{
    __shared__ __align__(16) char lds[16384];
    char* As = lds;
    char* Bs = lds + 8192;

    const int t = threadIdx.x;
    const int wid = t >> 6, lane = t & 63;
    const int brow = blockIdx.x * 128;
    const int bcol = blockIdx.y * 128;
    const int wr = wid >> 1, wc = wid & 1;

    f32x4 acc[4][4] = {};

    for (int k0 = 0; k0 < K; k0 += 32) {
#pragma unroll
        for (int j = 0; j < 2; ++j) {
            const int seg = wid * 2 + j;
            const int row = seg * 16 + (lane >> 2);
            const int clin = lane & 3;
            const int clog = clin ^ ((row >> 1) & 3);
            gload_lds16(A + (size_t)(brow + row) * lda + k0 + clog * 8,
                        As + seg * 1024);
            gload_lds16(Bt + (size_t)(bcol + row) * K + k0 + clog * 8,
                        Bs + seg * 1024);
        }
        __syncthreads();

        bf16x8 af[4], bfr[4];
#pragma unroll
        for (int m = 0; m < 4; ++m) {
            const int row = wr * 64 + m * 16 + (lane & 15);
            const int cl = (lane >> 4) ^ ((row >> 1) & 3);
            af[m] = *(const bf16x8*)(As + row * 64 + cl * 16);
        }
#pragma unroll
        for (int n = 0; n < 4; ++n) {
            const int row = wc * 64 + n * 16 + (lane & 15);
            const int cl = (lane >> 4) ^ ((row >> 1) & 3);
            bfr[n] = *(const bf16x8*)(Bs + row * 64 + cl * 16);
        }
#pragma unroll
        for (int m = 0; m < 4; ++m)
#pragma unroll
            for (int n = 0; n < 4; ++n)
                acc[m][n] = __builtin_amdgcn_mfma_f32_16x16x32_bf16(
                    af[m], bfr[n], acc[m][n], 0, 0, 0);
        __syncthreads();
    }

#pragma unroll
    for (int m = 0; m < 4; ++m) {
#pragma unroll
        for (int n = 0; n < 4; ++n) {
            const int col = bcol + wc * 64 + n * 16 + (lane & 15);
            const float bv = bias[col];
#pragma unroll
            for (int r = 0; r < 4; ++r) {
                const int row = brow + wr * 64 + m * 16 + (lane >> 4) * 4 + r;
                float v = acc[m][n][r] + bv;
                if (ACT == 1) v = fmaxf(v, 0.f);
                C[(size_t)row * ldc + col] = __float2bfloat16(v);
            }
        }
    }
}

// ---------------------------------------------------------------------------
// Weight/input prep
// ---------------------------------------------------------------------------
// Vectorized pad+cast: 300 = 75 float4 exactly; quads 75..79 are zero pad.
__global__ void prep_xpad_kernel(const float* __restrict__ x, bf16* __restrict__ xb)
{
    const int idx = blockIdx.x * 256 + threadIdx.x;   // grid covers N*80 exactly
    const int n = idx / 80, q = idx % 80;
    bf16x4 o;
    if (q < 75) {
        const float4 v = *(const float4*)(x + (size_t)n * IN_DIM + q * 4);
        o[0] = f_to_bfs(v.x); o[1] = f_to_bfs(v.y);
        o[2] = f_to_bfs(v.z); o[3] = f_to_bfs(v.w);
    } else {
        o[0] = 0; o[1] = 0; o[2] = 0; o[3] = 0;
    }
    *(bf16x4*)(xb + (size_t)n * KPAD + q * 4) = o;
}

__global__ void prep_encw_kernel(const float* __restrict__ syn_w,
                                 const float* __restrict__ ant_w,
                                 bf16* __restrict__ wt)
{
    const int c = blockIdx.x, k = threadIdx.x;
    float v = 0.f;
    if (k < IN_DIM) v = (c < HID) ? syn_w[k * HID + c] : ant_w[k * HID + (c - HID)];
    wt[c * KPAD + k] = __float2bfloat16(v);
}

__global__ void prep_fusw_kernel(const float* __restrict__ fw, bf16* __restrict__ wt)
{
    const int c = blockIdx.x, k = threadIdx.x;
    wt[c * 256 + k] = __float2bfloat16(fw[k * D_FUSED + c]);
}

__global__ __launch_bounds__(256) void prep_combw_kernel(
    const float* __restrict__ Wskip,
    const float* __restrict__ Wq,
    const float* __restrict__ Wk,
    const float* __restrict__ Wv,
    bf16* __restrict__ wt)
{
    __shared__ float tile[32][33];
    const int blk = blockIdx.x;
    const int l = blk >> 10, rem = blk & 1023;   // 64*16 = 1024 per layer
    const int cb = rem >> 4, kb = rem & 15;
    const int c0 = cb * 32;

    const int sel = c0 >> 9;
    const float* mat = (sel == 0) ? Wskip : (sel == 1) ? Wq : (sel == 2) ? Wk : Wv;
    const int cp0 = c0 & 511;

    const int j = threadIdx.x & 31;    // fast dim
    const int i0 = threadIdx.x >> 5;   // 0..7
#pragma unroll
    for (int s = 0; s < 4; ++s) {
        const int i = i0 + 8 * s;      // k within tile
        tile[i][j] = mat[((size_t)l * 512 + kb * 32 + i) * 512 + cp0 + j];
    }
    __syncthreads();
#pragma unroll
    for (int s = 0; s < 4; ++s) {
        const int jj = i0 + 8 * s;     // c within tile
        wt[((size_t)l * 2048 + c0 + jj) * 512 + kb * 32 + j] =
            __float2bfloat16(tile[j][jj]);
    }
}

__global__ void prep_bias_kernel(const float* __restrict__ syn_b,
                                 const float* __restrict__ ant_b,
                                 const float* __restrict__ bskip,
                                 const float* __restrict__ bq,
                                 const float* __restrict__ bk,
                                 const float* __restrict__ bv,
                                 float* __restrict__ benc,
                                 float* __restrict__ bcomb)
{
    const int i = blockIdx.x * 256 + threadIdx.x;
    if (i < 256) benc[i] = (i < HID) ? syn_b[i] : ant_b[i - HID];
    const int j = i - 256;
    if (j >= 0 && j < 6144) {
        const int l = j >> 11, c = j & 2047;
        const int sel = c >> 9, col = c & 511;
        const float* s = (sel == 0) ? bskip : (sel == 1) ? bq : (sel == 2) ? bk : bv;
        bcomb[j] = s[l * D_FUSED + col];
    }
}

// ---------------------------------------------------------------------------
// CSR build
// ---------------------------------------------------------------------------
__global__ void zero_int_kernel(int* __restrict__ p, int n)
{
    int i = blockIdx.x * 256 + threadIdx.x;
    if (i < n) p[i] = 0;
}

__global__ void hist_kernel(const int* __restrict__ dst, int* __restrict__ deg, int E)
{
    int e = blockIdx.x * 256 + threadIdx.x;
    if (e < E) atomicAdd(&deg[dst[e]], 1);
}

__global__ __launch_bounds__(256) void partial_sum_kernel(const int* __restrict__ deg,
                                                          int* __restrict__ part)
{
    int v = deg[blockIdx.x * 256 + threadIdx.x];
#pragma unroll
    for (int o = 32; o; o >>= 1) v += __shfl_xor(v, o);
    __shared__ int w4[4];
    if ((threadIdx.x & 63) == 0) w4[threadIdx.x >> 6] = v;
    __syncthreads();
    if (threadIdx.x == 0) part[blockIdx.x] = w4[0] + w4[1] + w4[2] + w4[3];
}

__global__ __launch_bounds__(128) void scan_part_kernel(int* __restrict__ part)
{
    __shared__ int s[128];
    const int t = threadIdx.x;
    s[t] = part[t];
    __syncthreads();
    for (int o = 1; o < 128; o <<= 1) {
        int v = (t >= o) ? s[t - o] : 0;
        __syncthreads();
        s[t] += v;
        __syncthreads();
    }
    part[t] = (t == 0) ? 0 : s[t - 1];  // exclusive
}

// off_kernel also zeroes cursor (saves the second half of the old zero_int
// launch; runs before scatter which is the only cursor consumer).
__global__ __launch_bounds__(256) void off_kernel(const int* __restrict__ deg,
                                                  const int* __restrict__ part,
                                                  int* __restrict__ off,
                                                  int* __restrict__ cursor)
{
    __shared__ int s[256];
    const int b = blockIdx.x, t = threadIdx.x;
    s[t] = deg[b * 256 + t];
    cursor[b * 256 + t] = 0;
    __syncthreads();
    for (int o = 1; o < 256; o <<= 1) {
        int v = (t >= o) ? s[t - o] : 0;
        __syncthreads();
        s[t] += v;
        __syncthreads();
    }
    const int excl = (t == 0) ? 0 : s[t - 1];
    off[b * 256 + t] = part[b] + excl;
    if (b == 127 && t == 255) off[N_NODES] = part[127] + s[255];
}

__global__ void scatter_kernel(const int* __restrict__ src, const int* __restrict__ dst,
                               const int* __restrict__ off, int* __restrict__ cursor,
                               int* __restrict__ csr_src, int E)
{
    int e = blockIdx.x * 256 + threadIdx.x;
    if (e < E) {
        int d = dst[e];
        int pos = atomicAdd(&cursor[d], 1);
        csr_src[off[d] + pos] = src[e];
    }
}

// ---------------------------------------------------------------------------
// 8-edge/iteration attention as TWO independent 4-edge sets; no online max
// (shift-invariant, logits bounded << 1). All of q,k,v fp8 in one
// [N][1536] buffer: q at +0, k at +512, v at +1024 (each hd*128+dim).
// Block = 256 = 4 waves; wave = head hd of node blockIdx.x.
// hout holds skip projection; add attention, relu, write back.
// ---------------------------------------------------------------------------
__global__ __launch_bounds__(256) void attn_kernel(
    const unsigned char* __restrict__ qkvb, bf16* __restrict__ hout,
    const int* __restrict__ off, const int* __restrict__ csr)
{
    const int n = blockIdx.x;
    const int hd = threadIdx.x >> 6;
    const int lane = threadIdx.x & 63;
    const int g = lane >> 4, sub = lane & 15;
    const float scale = 0.08838834764831845f;  // 1/sqrt(128)

    float qf[8];
    fp8x8_to_f32(*(const uint2*)(qkvb + (size_t)n * 1536 + hd * 128 + sub * 8), qf);

    float zA = 0.f, zB = 0.f;
    float accA[8] = {}, accB[8] = {};

    const int s0 = off[n], s1 = off[n + 1];
    for (int e0 = s0; e0 < s1; e0 += 8) {
        const int ea = e0 + g;
        const int eb = e0 + 4 + g;
        const bool va = (ea < s1);
        const bool vb = (eb < s1);
        const int sa = va ? csr[ea] : 0;
        const int sb = vb ? csr[eb] : 0;
        const unsigned char* pa = qkvb + (size_t)sa * 1536 + hd * 128 + sub * 8;
        const unsigned char* pb = qkvb + (size_t)sb * 1536 + hd * 128 + sub * 8;

        const uint2 kwa = *(const uint2*)(pa + 512);
        const uint2 kwb = *(const uint2*)(pb + 512);
        const uint2 vwa = *(const uint2*)(pa + 1024);
        const uint2 vwb = *(const uint2*)(pb + 1024);

        float kfa[8], kfb[8];
        fp8x8_to_f32(kwa, kfa);
        fp8x8_to_f32(kwb, kfb);
        float da = 0.f, db = 0.f;
#pragma unroll
        for (int j = 0; j < 8; ++j) {
            da = fmaf(qf[j], kfa[j], da);
            db = fmaf(qf[j], kfb[j], db);
        }
        da += __shfl_xor(da, 1);  db += __shfl_xor(db, 1);
        da += __shfl_xor(da, 2);  db += __shfl_xor(db, 2);
        da += __shfl_xor(da, 4);  db += __shfl_xor(db, 4);
        da += __shfl_xor(da, 8);  db += __shfl_xor(db, 8);

        const float wa = va ? __expf(da * scale) : 0.f;
        const float wb = vb ? __expf(db * scale) : 0.f;
        zA += wa;
        zB += wb;

        float vfa[8], vfb[8];
        fp8x8_to_f32(vwa, vfa);
        fp8x8_to_f32(vwb, vfb);
#pragma unroll
        for (int j = 0; j < 8; ++j) {
            accA[j] = fmaf(wa, vfa[j], accA[j]);
            accB[j] = fmaf(wb, vfb[j], accB[j]);
        }
    }

    float zz = zA + zB;
    zz += __shfl_xor(zz, 16);
    zz += __shfl_xor(zz, 32);
    const float inv = 1.f / (zz + 1e-16f);

    float o[8];
#pragma unroll
    for (int j = 0; j < 8; ++j) {
        float a = accA[j] + accB[j];
        a += __shfl_xor(a, 16);
        a += __shfl_xor(a, 32);
        o[j] = a * inv;
    }

    if (g == 0) {
        const size_t ob = (size_t)n * D_FUSED + hd * HID + sub * 8;
        const bf16x8 sk = *(const bf16x8*)(hout + ob);
        bf16x8 res;
#pragma unroll
        for (int j = 0; j < 8; ++j)
            res[j] = f_to_bfs(fmaxf(o[j] + bfs_to_f(sk[j]), 0.f));
        *(bf16x8*)(hout + ob) = res;
    }
}

// ---------------------------------------------------------------------------
// FUSED mean-pool + classifier (round-21): block g pools its node range
// into shared pooled[512], then threads 0..127 run the classifier from
// shared — removes one launch + the global pooled round-trip.
// ---------------------------------------------------------------------------
__global__ __launch_bounds__(256) void pool_cls_kernel(
    const bf16* __restrict__ h, const int* __restrict__ batch,
    const float* __restrict__ w1, const float* __restrict__ b1,
    const float* __restrict__ w2, const float* __restrict__ b2,
    float* __restrict__ out)
{
    const int g = blockIdx.x;
    int a = 0, b = N_NODES;
    while (a < b) { int mid = (a + b) >> 1; if (batch[mid] < g) a = mid + 1; else b = mid; }
    const int start = a;
    b = N_NODES;
    while (a < b) { int mid = (a + b) >> 1; if (batch[mid] < g + 1) a = mid + 1; else b = mid; }
    const int end = a;
    const float invc = 1.f / fmaxf((float)(end - start), 1.f);

    const int nl = threadIdx.x >> 6;   // node lane (wave)
    const int dl = threadIdx.x & 63;   // dim lane: dims dl*8..dl*8+7

    float s[8] = {};
    for (int nidx = start + nl; nidx < end; nidx += 4) {
        const bf16x8 v = *(const bf16x8*)(h + (size_t)nidx * D_FUSED + dl * 8);
#pragma unroll
        for (int j = 0; j < 8; ++j) s[j] += bfs_to_f(v[j]);
    }

    __shared__ float red[4][512];
    __shared__ float pooled[512];
#pragma unroll
    for (int j = 0; j < 8; ++j) red[nl][dl * 8 + j] = s[j];
    __syncthreads();
    if (nl == 0) {
#pragma unroll
        for (int j = 0; j < 8; ++j) {
            const int d = dl * 8 + j;
            pooled[d] = (red[0][d] + red[1][d] + red[2][d] + red[3][d]) * invc;
        }
    }
    __syncthreads();

    // classifier from shared pooled: threads 0..127 = columns of w1
    float val = 0.f;
    if (threadIdx.x < 128) {
        const int j = threadIdx.x;
        float acc = 0.f;
        for (int i = 0; i < D_FUSED; ++i) acc = fmaf(pooled[i], w1[i * HID + j], acc);
        const float hid = fmaxf(acc + b1[j], 0.f);
        val = hid * w2[j];
    }
#pragma unroll
    for (int o = 32; o; o >>= 1) val += __shfl_xor(val, o);
    __shared__ float ws2[2];
    if ((threadIdx.x & 63) == 0 && threadIdx.x < 128) ws2[threadIdx.x >> 6] = val;
    __syncthreads();
    if (threadIdx.x == 0) {
        const float sum = ws2[0] + ws2[1] + b2[0];
        out[g] = 1.f / (1.f + __expf(-sum));
    }
}

// ---------------------------------------------------------------------------
extern "C" void kernel_launch(void* const* d_in, const int* in_sizes, int n_in,
                              void* d_out, int out_size, void* d_ws, size_t ws_size,
                              hipStream_t stream)
{
    const float* x        = (const float*)d_in[0];
    const int*   ei       = (const int*)d_in[1];
    const int*   batch    = (const int*)d_in[2];
    const float* syn_w    = (const float*)d_in[3];
    const float* syn_b    = (const float*)d_in[4];
    const float* ant_w    = (const float*)d_in[5];
    const float* ant_b    = (const float*)d_in[6];
    const float* fusion_w = (const float*)d_in[7];
    const float* fusion_b = (const float*)d_in[8];
    const float* Wq       = (const float*)d_in[9];
    const float* bq       = (const float*)d_in[10];
    const float* Wk       = (const float*)d_in[11];
    const float* bk       = (const float*)d_in[12];
    const float* Wv       = (const float*)d_in[13];
    const float* bv       = (const float*)d_in[14];
    const float* Wskip    = (const float*)d_in[15];
    const float* bskip    = (const float*)d_in[16];
    const float* cls_w1   = (const float*)d_in[17];
    const float* cls_b1   = (const float*)d_in[18];
    const float* cls_w2   = (const float*)d_in[19];
    const float* cls_b2   = (const float*)d_in[20];

    const int* src = ei;
    const int* dst = ei + N_EDGES;

    // ---- workspace layout (~125 MB) ----
    const size_t NV = (size_t)N_NODES * D_FUSED;
    bf16* hA    = (bf16*)d_ws;                         // N*512 bf16
    bf16* hB    = hA + NV;                             // N*512 bf16
    unsigned char* qkv = (unsigned char*)(hB + NV);    // N*1536 fp8 (q|k|v)
    bf16* wenc  = (bf16*)(qkv + (size_t)N_NODES * 1536);     // 256*320
    bf16* wfus  = wenc + 256 * KPAD;                   // 512*256
    bf16* wcomb = wfus + 512 * 256;                    // 3*2048*512
    float* benc = (float*)(wcomb + (size_t)3 * 2048 * 512);  // 256
    float* bcomb = benc + 256;                         // 6144
    int* deg    = (int*)(bcomb + 6144);                // N
    int* cursor = deg + N_NODES;                       // N
    int* part   = cursor + N_NODES;                    // 128
    int* off    = part + 128;                          // N+1
    int* csr    = off + N_NODES + 1;                   // E

    bf16* xb   = (bf16*)qkv;  // N*320 bf16, dead before layer GEMMs
    bf16* tenc = hB;          // N*256, dead before first layer GEMM

    // ---- CSR build (cursor zeroed inside off_kernel) ----
    zero_int_kernel<<<(N_NODES + 255) / 256, 256, 0, stream>>>(deg, N_NODES);
    hist_kernel<<<N_EDGES / 256, 256, 0, stream>>>(dst, deg, N_EDGES);
    partial_sum_kernel<<<128, 256, 0, stream>>>(deg, part);
    scan_part_kernel<<<1, 128, 0, stream>>>(part);
    off_kernel<<<128, 256, 0, stream>>>(deg, part, off, cursor);
    scatter_kernel<<<N_EDGES / 256, 256, 0, stream>>>(src, dst, off, cursor, csr, N_EDGES);

    // ---- prep ----
    prep_xpad_kernel<<<(N_NODES * 80) / 256, 256, 0, stream>>>(x, xb);
    prep_encw_kernel<<<256, KPAD, 0, stream>>>(syn_w, ant_w, wenc);
    prep_fusw_kernel<<<512, 256, 0, stream>>>(fusion_w, wfus);
    prep_combw_kernel<<<3072, 256, 0, stream>>>(Wskip, Wq, Wk, Wv, wcomb);
    prep_bias_kernel<<<25, 256, 0, stream>>>(syn_b, ant_b, bskip, bq, bk, bv, benc, bcomb);

    // ---- encoder ----
    mfma_gemm<1><<<dim3(N_NODES / 128, 2), 256, 0, stream>>>(
        xb, KPAD, wenc, benc, tenc, 256, KPAD);
    mfma_gemm256<256, 0, 0><<<256, 512, 0, stream>>>(
        tenc, 256, wfus, fusion_b, hA, D_FUSED, hA, D_FUSED, D_FUSED, nullptr, 2);

    // ---- transformer layers ----
    bf16* hcur = hA;
    bf16* hnew = hB;
    for (int l = 0; l < N_LAYERS; ++l) {
        mfma_gemm256<512, 0, 1><<<1024, 512, 0, stream>>>(
            hcur, D_FUSED, wcomb + (size_t)l * 2048 * D_FUSED,
            bcomb + (size_t)l * 2048,
            hnew, D_FUSED, nullptr, 0, 512, qkv, 8);
        attn_kernel<<<N_NODES, 256, 0, stream>>>(qkv, hnew, off, csr);
        bf16* tmp = hcur; hcur = hnew; hnew = tmp;
    }

    // ---- fused pool + classify ----
    pool_cls_kernel<<<N_GRAPHS, 256, 0, stream>>>(hcur, batch, cls_w1, cls_b1,
                                                  cls_w2, cls_b2, (float*)d_out);
}

// Round 22
// 554.394 us; speedup vs baseline: 4.4230x; 1.0084x over previous
//
#include <hip/hip_runtime.h>
#include <hip/hip_bf16.h>
#include <hip/hip_fp8.h>
#include <math.h>

#define N_NODES 32768
#define N_EDGES 262144
#define N_GRAPHS 512
#define IN_DIM 300
#define KPAD 320
#define HID 128
#define HEADS 4
#define D_FUSED 512
#define N_LAYERS 3

typedef __hip_bfloat16 bf16;
typedef short bf16x8 __attribute__((ext_vector_type(8)));
typedef short bf16x4 __attribute__((ext_vector_type(4)));
typedef float f32x4 __attribute__((ext_vector_type(4)));
typedef float f32x2 __attribute__((ext_vector_type(2)));

__device__ __forceinline__ float bfs_to_f(short s)
{
    unsigned u = ((unsigned)(unsigned short)s) << 16;
    return __builtin_bit_cast(float, u);
}

__device__ __forceinline__ short f_to_bfs(float v)
{
    return (short)__builtin_bit_cast(unsigned short, __float2bfloat16(v));
}

__device__ __forceinline__ void bf8_to_f32(bf16x8 v, float* f)
{
#pragma unroll
    for (int j = 0; j < 8; ++j) f[j] = bfs_to_f(v[j]);
}

__device__ __forceinline__ unsigned char f32_to_fp8(float v)
{
#if __has_builtin(__builtin_amdgcn_cvt_pk_fp8_f32)
    int p = __builtin_amdgcn_cvt_pk_fp8_f32(v, v, 0, false);
    return (unsigned char)(p & 0xff);
#else
    __hip_fp8_e4m3 t(v);
    return (unsigned char)t.__x;
#endif
}

__device__ __forceinline__ void fp8x8_to_f32(uint2 w, float* f)
{
#if __has_builtin(__builtin_amdgcn_cvt_pk_f32_fp8)
    f32x2 a = __builtin_amdgcn_cvt_pk_f32_fp8((int)w.x, false);
    f32x2 b = __builtin_amdgcn_cvt_pk_f32_fp8((int)w.x, true);
    f32x2 c = __builtin_amdgcn_cvt_pk_f32_fp8((int)w.y, false);
    f32x2 d = __builtin_amdgcn_cvt_pk_f32_fp8((int)w.y, true);
    f[0] = a.x; f[1] = a.y; f[2] = b.x; f[3] = b.y;
    f[4] = c.x; f[5] = c.y; f[6] = d.x; f[7] = d.y;
#else
    const unsigned char* p = (const unsigned char*)&w;
#pragma unroll
    for (int j = 0; j < 8; ++j) {
        __hip_fp8_e4m3 t;
        t.__x = (__hip_fp8_storage_t)p[j];
        f[j] = (float)t;
    }
#endif
}

__device__ __forceinline__ void gload_lds16(const void* g, void* l)
{
    __builtin_amdgcn_global_load_lds(
        (const __attribute__((address_space(1))) void*)g,
        (__attribute__((address_space(3))) void*)l, 16, 0, 0);
}

// ---------------------------------------------------------------------------
// 128x256-tile MFMA GEMM, BK=32, ROUND-22: TRIPLE-buffered LDS (3 x 24 KB)
// with 2-tile-deep prefetch — iteration kt stages tile kt+2 and waits
// vmcnt(6) (tiles kt+1, kt+2 = 6 loads stay in flight), giving each load
// TWO tiles of compute (~600-800 cyc) to cover HBM/L2 latency. This is the
// latency-coverage fix the 1-tile-deep r16/r18 schedules lacked.
// Base: r18 validated kernel (8 waves 2Mx4N, 64x64/wave, acc=64 VGPRs,
// no spill). Buffer-rewrite hazard: iter kt+1 overwrites buf kt%3, guarded
// by iter kt's tile-end barrier. kt%3 is compile-time after full unroll.
// EPI=0: col<csplit -> C0 (bf16, ldc0), else C1 (bf16, ldc1, col-csplit).
// EPI=1: bcol<512 -> C0 bf16 (ld ldc0); else -> C2 fp8 e4m3, ld 1536,
//        at col-512 (unified q|k|v fp8 buffer).
// Requires M%128==0, N%256==0, K%32==0, K>=96, 16B-aligned rows.
// ---------------------------------------------------------------------------
template <int K, int ACT, int EPI>
__global__ __launch_bounds__(512, 4) void mfma_gemm128(
    const bf16* __restrict__ A, int lda,
    const bf16* __restrict__ Bt,
    const float* __restrict__ bias,
    bf16* __restrict__ C0, int ldc0,
    bf16* __restrict__ C1, int ldc1, int csplit,
    unsigned char* __restrict__ C2,
    int nbx)
{
    __shared__ __align__(16) char lds[73728];
    // buf b at b*24576: A-slab 8 KB at +0, B-slab 16 KB at +8192

    const int t = threadIdx.x;
    const int wid = t >> 6, lane = t & 63;
    const int hi = lane >> 4, li = lane & 15;
    const int wr = wid >> 2, wc = wid & 3;   // 2M x 4N of 64x64

    int wg = blockIdx.x;
    if ((gridDim.x & 7) == 0) {              // bijective XCD swizzle
        const int cpx = gridDim.x >> 3;
        wg = (wg & 7) * cpx + (wg >> 3);
    }
    const int mb = wg / nbx, nb = wg % nbx;
    const int brow = mb * 128, bcol = nb * 256;
    constexpr int NT = K >> 5;

    // A tile: 128 rows x 4 slots = 512 chunks -> 1 chunk/thread (chunk t).
    // B tile: 256 rows x 4 slots = 1024 chunks -> 2/thread (t, t+512).
    // chunk c: row = c>>2, slot = c&3, global col-slot = (c&3)^((row>>1)&3),
    // linear DMA dest = c*16.
    const int rowA = t >> 2;
    const int slA = (((t & 3) ^ ((rowA >> 1) & 3)) * 8);
    const int cB1 = t + 512;
    const int rowB1 = cB1 >> 2;
    const int slB1 = (((cB1 & 3) ^ ((rowB1 >> 1) & 3)) * 8);

    const bf16* gA  = A  + (size_t)(brow + rowA)  * lda + slA;
    const bf16* gB0 = Bt + (size_t)(bcol + rowA)  * K   + slA;
    const bf16* gB1 = Bt + (size_t)(bcol + rowB1) * K   + slB1;

    auto stage = [&](int buf, int kt1) {
        const int ko = kt1 * 32;
        const int base = buf * 24576;
        gload_lds16(gA  + ko, lds + base + wid * 1024);
        gload_lds16(gB0 + ko, lds + base + 8192 + wid * 1024);
        gload_lds16(gB1 + ko, lds + base + 16384 + wid * 1024);
    };

    f32x4 acc[4][4] = {};

    // prologue: 2 tiles in flight
    stage(0, 0);
    if (NT > 1) stage(1, 1);

#pragma unroll
    for (int kt = 0; kt < NT; ++kt) {
        const int b = kt % 3;
        const char* Aslab = lds + b * 24576;
        const char* Bslab = Aslab + 8192;

        // deep prefetch: issue tile kt+2, then counted wait so tile kt's 3
        // loads are retired (kt+1's 3 + kt+2's 3 = 6 stay in flight).
        if (kt < NT - 2) {
            stage((kt + 2) % 3, kt + 2);
            asm volatile("s_waitcnt vmcnt(6)" ::: "memory");
        } else if (kt == NT - 2) {
            asm volatile("s_waitcnt vmcnt(3)" ::: "memory");
        } else {
            asm volatile("s_waitcnt vmcnt(0)" ::: "memory");
        }
        __builtin_amdgcn_s_barrier();        // all waves' DMA for tile kt landed
        __builtin_amdgcn_sched_barrier(0);

        bf16x8 bfrag[4];
#pragma unroll
        for (int n = 0; n < 4; ++n) {
            const int row = wc * 64 + n * 16 + li;
            bfrag[n] = *(const bf16x8*)(
                Bslab + row * 64 + ((hi ^ ((row >> 1) & 3)) << 4));
        }
        bf16x8 af[4];
#pragma unroll
        for (int m = 0; m < 4; ++m) {
            const int row = wr * 64 + m * 16 + li;
            af[m] = *(const bf16x8*)(
                Aslab + row * 64 + ((hi ^ ((row >> 1) & 3)) << 4));
        }
        __builtin_amdgcn_s_setprio(1);
#pragma unroll
        for (int m = 0; m < 4; ++m)
#pragma unroll
            for (int n = 0; n < 4; ++n)
                acc[m][n] = __builtin_amdgcn_mfma_f32_16x16x32_bf16(
                    af[m], bfrag[n], acc[m][n], 0, 0, 0);
        __builtin_amdgcn_s_setprio(0);

        // tile end: buf kt%3 fully consumed before iter kt+1 stages
        // tile kt+3 (same buffer) into it.
        __builtin_amdgcn_s_barrier();
        __builtin_amdgcn_sched_barrier(0);
    }

    // epilogue: C/D layout col=li, row=hi*4+r; destination block-uniform
    if (EPI == 0) {
        const bool lo = (bcol < csplit);
        bf16* Cd = lo ? C0 : C1;
        const int ldc = lo ? ldc0 : ldc1;
        const int csub = lo ? 0 : csplit;
#pragma unroll
        for (int m = 0; m < 4; ++m)
#pragma unroll
            for (int n = 0; n < 4; ++n) {
                const int col = bcol + wc * 64 + n * 16 + li;
                const float bv = bias[col];
#pragma unroll
                for (int r = 0; r < 4; ++r) {
                    const int row = brow + wr * 64 + m * 16 + hi * 4 + r;
                    float v = acc[m][n][r] + bv;
                    if (ACT == 1) v = fmaxf(v, 0.f);
                    Cd[(size_t)row * ldc + (col - csub)] = __float2bfloat16(v);
                }
            }
    } else if (bcol < 512) {
#pragma unroll
        for (int m = 0; m < 4; ++m)
#pragma unroll
            for (int n = 0; n < 4; ++n) {
                const int col = bcol + wc * 64 + n * 16 + li;
                const float bv = bias[col];
#pragma unroll
                for (int r = 0; r < 4; ++r) {
                    const int row = brow + wr * 64 + m * 16 + hi * 4 + r;
                    C0[(size_t)row * ldc0 + col] = __float2bfloat16(acc[m][n][r] + bv);
                }
            }
    } else {
        // fp8 q|k|v unified buffer, ld 1536, at col-512
#pragma unroll
        for (int m = 0; m < 4; ++m)
#pragma unroll
            for (int n = 0; n < 4; ++n) {
                const int col = bcol + wc * 64 + n * 16 + li;
                const float bv = bias[col];
#pragma unroll
                for (int r = 0; r < 4; ++r) {
                    const int row = brow + wr * 64 + m * 16 + hi * 4 + r;
                    C2[(size_t)row * 1536 + (col - 512)] = f32_to_fp8(acc[m][n][r] + bv);
                }
            }
    }
}

// ---------------------------------------------------------------------------
// 128x128 MFMA GEMM (m97 structure) — kept for the small-N encoder GEMM.
// ---------------------------------------------------------------------------
template <int ACT>
__global__ __launch_bounds__(256) void mfma_gemm(
    const bf16* __restrict__ A, int lda,
    const bf16* __restrict__ Bt,
    const float* __restrict__ bias,
    bf16* __restrict__ C, int ldc, int K)
{
    __shared__ __align__(16) char lds[16384];
    char* As = lds;
    char* Bs = lds + 8192;

    const int t = threadIdx.x;
    const int wid = t >> 6, lane = t & 63;
    const int brow = blockIdx.x * 128;
    const int bcol = blockIdx.y * 128;
    const int wr = wid >> 1, wc = wid & 1;

    f32x4 acc[4][4] = {};

    for (int k0 = 0; k0 < K; k0 += 32) {
#pragma unroll
        for (int j = 0; j < 2; ++j) {
            const int seg = wid * 2 + j;
            const int row = seg * 16 + (lane >> 2);
            const int clin = lane & 3;
            const int clog = clin ^ ((row >> 1) & 3);
            gload_lds16(A + (size_t)(brow + row) * lda + k0 + clog * 8,
                        As + seg * 1024);
            gload_lds16(Bt + (size_t)(bcol + row) * K + k0 + clog * 8,
                        Bs + seg * 1024);
        }
        __syncthreads();

        bf16x8 af[4], bfr[4];
#pragma unroll
        for (int m = 0; m < 4; ++m) {
            const int row = wr * 64 + m * 16 + (lane & 15);
            const int cl = (lane >> 4) ^ ((row >> 1) & 3);
            af[m] = *(const bf16x8*)(As + row * 64 + cl * 16);
        }
#pragma unroll
        for (int n = 0; n < 4; ++n) {
            const int row = wc * 64 + n * 16 + (lane & 15);
            const int cl = (lane >> 4) ^ ((row >> 1) & 3);
            bfr[n] = *(const bf16x8*)(Bs + row * 64 + cl * 16);
        }
#pragma unroll
        for (int m = 0; m < 4; ++m)
#pragma unroll
            for (int n = 0; n < 4; ++n)
                acc[m][n] = __builtin_amdgcn_mfma_f32_16x16x32_bf16(
                    af[m], bfr[n], acc[m][n], 0, 0, 0);
        __syncthreads();
    }

#pragma unroll
    for (int m = 0; m < 4; ++m) {
#pragma unroll
        for (int n = 0; n < 4; ++n) {
            const int col = bcol + wc * 64 + n * 16 + (lane & 15);
            const float bv = bias[col];
#pragma unroll
            for (int r = 0; r < 4; ++r) {
                const int row = brow + wr * 64 + m * 16 + (lane >> 4) * 4 + r;
                float v = acc[m][n][r] + bv;
                if (ACT == 1) v = fmaxf(v, 0.f);
                C[(size_t)row * ldc + col] = __float2bfloat16(v);
            }
        }
    }
}

// ---------------------------------------------------------------------------
// Weight/input prep
// ---------------------------------------------------------------------------
// Vectorized pad+cast: 300 = 75 float4 exactly; quads 75..79 are zero pad.
__global__ void prep_xpad_kernel(const float* __restrict__ x, bf16* __restrict__ xb)
{
    const int idx = blockIdx.x * 256 + threadIdx.x;   // grid covers N*80 exactly
    const int n = idx / 80, q = idx % 80;
    bf16x4 o;
    if (q < 75) {
        const float4 v = *(const float4*)(x + (size_t)n * IN_DIM + q * 4);
        o[0] = f_to_bfs(v.x); o[1] = f_to_bfs(v.y);
        o[2] = f_to_bfs(v.z); o[3] = f_to_bfs(v.w);
    } else {
        o[0] = 0; o[1] = 0; o[2] = 0; o[3] = 0;
    }
    *(bf16x4*)(xb + (size_t)n * KPAD + q * 4) = o;
}

__global__ void prep_encw_kernel(const float* __restrict__ syn_w,
                                 const float* __restrict__ ant_w,
                                 bf16* __restrict__ wt)
{
    const int c = blockIdx.x, k = threadIdx.x;
    float v = 0.f;
    if (k < IN_DIM) v = (c < HID) ? syn_w[k * HID + c] : ant_w[k * HID + (c - HID)];
    wt[c * KPAD + k] = __float2bfloat16(v);
}

__global__ void prep_fusw_kernel(const float* __restrict__ fw, bf16* __restrict__ wt)
{
    const int c = blockIdx.x, k = threadIdx.x;
    wt[c * 256 + k] = __float2bfloat16(fw[k * D_FUSED + c]);
}

__global__ __launch_bounds__(256) void prep_combw_kernel(
    const float* __restrict__ Wskip,
    const float* __restrict__ Wq,
    const float* __restrict__ Wk,
    const float* __restrict__ Wv,
    bf16* __restrict__ wt)
{
    __shared__ float tile[32][33];
    const int blk = blockIdx.x;
    const int l = blk >> 10, rem = blk & 1023;   // 64*16 = 1024 per layer
    const int cb = rem >> 4, kb = rem & 15;
    const int c0 = cb * 32;

    const int sel = c0 >> 9;
    const float* mat = (sel == 0) ? Wskip : (sel == 1) ? Wq : (sel == 2) ? Wk : Wv;
    const int cp0 = c0 & 511;

    const int j = threadIdx.x & 31;    // fast dim
    const int i0 = threadIdx.x >> 5;   // 0..7
#pragma unroll
    for (int s = 0; s < 4; ++s) {
        const int i = i0 + 8 * s;      // k within tile
        tile[i][j] = mat[((size_t)l * 512 + kb * 32 + i) * 512 + cp0 + j];
    }
    __syncthreads();
#pragma unroll
    for (int s = 0; s < 4; ++s) {
        const int jj = i0 + 8 * s;     // c within tile
        wt[((size_t)l * 2048 + c0 + jj) * 512 + kb * 32 + j] =
            __float2bfloat16(tile[j][jj]);
    }
}

__global__ void prep_bias_kernel(const float* __restrict__ syn_b,
                                 const float* __restrict__ ant_b,
                                 const float* __restrict__ bskip,
                                 const float* __restrict__ bq,
                                 const float* __restrict__ bk,
                                 const float* __restrict__ bv,
                                 float* __restrict__ benc,
                                 float* __restrict__ bcomb)
{
    const int i = blockIdx.x * 256 + threadIdx.x;
    if (i < 256) benc[i] = (i < HID) ? syn_b[i] : ant_b[i - HID];
    const int j = i - 256;
    if (j >= 0 && j < 6144) {
        const int l = j >> 11, c = j & 2047;
        const int sel = c >> 9, col = c & 511;
        const float* s = (sel == 0) ? bskip : (sel == 1) ? bq : (sel == 2) ? bk : bv;
        bcomb[j] = s[l * D_FUSED + col];
    }
}

// ---------------------------------------------------------------------------
// CSR build
// ---------------------------------------------------------------------------
__global__ void zero_int_kernel(int* __restrict__ p, int n)
{
    int i = blockIdx.x * 256 + threadIdx.x;
    if (i < n) p[i] = 0;
}

__global__ void hist_kernel(const int* __restrict__ dst, int* __restrict__ deg, int E)
{
    int e = blockIdx.x * 256 + threadIdx.x;
    if (e < E) atomicAdd(&deg[dst[e]], 1);
}

__global__ __launch_bounds__(256) void partial_sum_kernel(const int* __restrict__ deg,
                                                          int* __restrict__ part)
{
    int v = deg[blockIdx.x * 256 + threadIdx.x];
#pragma unroll
    for (int o = 32; o; o >>= 1) v += __shfl_xor(v, o);
    __shared__ int w4[4];
    if ((threadIdx.x & 63) == 0) w4[threadIdx.x >> 6] = v;
    __syncthreads();
    if (threadIdx.x == 0) part[blockIdx.x] = w4[0] + w4[1] + w4[2] + w4[3];
}

__global__ __launch_bounds__(128) void scan_part_kernel(int* __restrict__ part)
{
    __shared__ int s[128];
    const int t = threadIdx.x;
    s[t] = part[t];
    __syncthreads();
    for (int o = 1; o < 128; o <<= 1) {
        int v = (t >= o) ? s[t - o] : 0;
        __syncthreads();
        s[t] += v;
        __syncthreads();
    }
    part[t] = (t == 0) ? 0 : s[t - 1];  // exclusive
}

// off_kernel also zeroes cursor.
__global__ __launch_bounds__(256) void off_kernel(const int* __restrict__ deg,
                                                  const int* __restrict__ part,
                                                  int* __restrict__ off,
                                                  int* __restrict__ cursor)
{
    __shared__ int s[256];
    const int b = blockIdx.x, t = threadIdx.x;
    s[t] = deg[b * 256 + t];
    cursor[b * 256 + t] = 0;
    __syncthreads();
    for (int o = 1; o < 256; o <<= 1) {
        int v = (t >= o) ? s[t - o] : 0;
        __syncthreads();
        s[t] += v;
        __syncthreads();
    }
    const int excl = (t == 0) ? 0 : s[t - 1];
    off[b * 256 + t] = part[b] + excl;
    if (b == 127 && t == 255) off[N_NODES] = part[127] + s[255];
}

__global__ void scatter_kernel(const int* __restrict__ src, const int* __restrict__ dst,
                               const int* __restrict__ off, int* __restrict__ cursor,
                               int* __restrict__ csr_src, int E)
{
    int e = blockIdx.x * 256 + threadIdx.x;
    if (e < E) {
        int d = dst[e];
        int pos = atomicAdd(&cursor[d], 1);
        csr_src[off[d] + pos] = src[e];
    }
}

// ---------------------------------------------------------------------------
// 8-edge/iteration attention as TWO independent 4-edge sets; no online max
// (shift-invariant, logits bounded << 1). All of q,k,v fp8 in one
// [N][1536] buffer: q at +0, k at +512, v at +1024 (each hd*128+dim).
// Block = 256 = 4 waves; wave = head hd of node blockIdx.x.
// hout holds skip projection; add attention, relu, write back.
// ---------------------------------------------------------------------------
__global__ __launch_bounds__(256) void attn_kernel(
    const unsigned char* __restrict__ qkvb, bf16* __restrict__ hout,
    const int* __restrict__ off, const int* __restrict__ csr)
{
    const int n = blockIdx.x;
    const int hd = threadIdx.x >> 6;
    const int lane = threadIdx.x & 63;
    const int g = lane >> 4, sub = lane & 15;
    const float scale = 0.08838834764831845f;  // 1/sqrt(128)

    float qf[8];
    fp8x8_to_f32(*(const uint2*)(qkvb + (size_t)n * 1536 + hd * 128 + sub * 8), qf);

    float zA = 0.f, zB = 0.f;
    float accA[8] = {}, accB[8] = {};

    const int s0 = off[n], s1 = off[n + 1];
    for (int e0 = s0; e0 < s1; e0 += 8) {
        const int ea = e0 + g;
        const int eb = e0 + 4 + g;
        const bool va = (ea < s1);
        const bool vb = (eb < s1);
        const int sa = va ? csr[ea] : 0;
        const int sb = vb ? csr[eb] : 0;
        const unsigned char* pa = qkvb + (size_t)sa * 1536 + hd * 128 + sub * 8;
        const unsigned char* pb = qkvb + (size_t)sb * 1536 + hd * 128 + sub * 8;

        const uint2 kwa = *(const uint2*)(pa + 512);
        const uint2 kwb = *(const uint2*)(pb + 512);
        const uint2 vwa = *(const uint2*)(pa + 1024);
        const uint2 vwb = *(const uint2*)(pb + 1024);

        float kfa[8], kfb[8];
        fp8x8_to_f32(kwa, kfa);
        fp8x8_to_f32(kwb, kfb);
        float da = 0.f, db = 0.f;
#pragma unroll
        for (int j = 0; j < 8; ++j) {
            da = fmaf(qf[j], kfa[j], da);
            db = fmaf(qf[j], kfb[j], db);
        }
        da += __shfl_xor(da, 1);  db += __shfl_xor(db, 1);
        da += __shfl_xor(da, 2);  db += __shfl_xor(db, 2);
        da += __shfl_xor(da, 4);  db += __shfl_xor(db, 4);
        da += __shfl_xor(da, 8);  db += __shfl_xor(db, 8);

        const float wa = va ? __expf(da * scale) : 0.f;
        const float wb = vb ? __expf(db * scale) : 0.f;
        zA += wa;
        zB += wb;

        float vfa[8], vfb[8];
        fp8x8_to_f32(vwa, vfa);
        fp8x8_to_f32(vwb, vfb);
#pragma unroll
        for (int j = 0; j < 8; ++j) {
            accA[j] = fmaf(wa, vfa[j], accA[j]);
            accB[j] = fmaf(wb, vfb[j], accB[j]);
        }
    }

    float zz = zA + zB;
    zz += __shfl_xor(zz, 16);
    zz += __shfl_xor(zz, 32);
    const float inv = 1.f / (zz + 1e-16f);

    float o[8];
#pragma unroll
    for (int j = 0; j < 8; ++j) {
        float a = accA[j] + accB[j];
        a += __shfl_xor(a, 16);
        a += __shfl_xor(a, 32);
        o[j] = a * inv;
    }

    if (g == 0) {
        const size_t ob = (size_t)n * D_FUSED + hd * HID + sub * 8;
        const bf16x8 sk = *(const bf16x8*)(hout + ob);
        bf16x8 res;
#pragma unroll
        for (int j = 0; j < 8; ++j)
            res[j] = f_to_bfs(fmaxf(o[j] + bfs_to_f(sk[j]), 0.f));
        *(bf16x8*)(hout + ob) = res;
    }
}

// ---------------------------------------------------------------------------
// FUSED mean-pool + classifier.
// ---------------------------------------------------------------------------
__global__ __launch_bounds__(256) void pool_cls_kernel(
    const bf16* __restrict__ h, const int* __restrict__ batch,
    const float* __restrict__ w1, const float* __restrict__ b1,
    const float* __restrict__ w2, const float* __restrict__ b2,
    float* __restrict__ out)
{
    const int g = blockIdx.x;
    int a = 0, b = N_NODES;
    while (a < b) { int mid = (a + b) >> 1; if (batch[mid] < g) a = mid + 1; else b = mid; }
    const int start = a;
    b = N_NODES;
    while (a < b) { int mid = (a + b) >> 1; if (batch[mid] < g + 1) a = mid + 1; else b = mid; }
    const int end = a;
    const float invc = 1.f / fmaxf((float)(end - start), 1.f);

    const int nl = threadIdx.x >> 6;   // node lane (wave)
    const int dl = threadIdx.x & 63;   // dim lane: dims dl*8..dl*8+7

    float s[8] = {};
    for (int nidx = start + nl; nidx < end; nidx += 4) {
        const bf16x8 v = *(const bf16x8*)(h + (size_t)nidx * D_FUSED + dl * 8);
#pragma unroll
        for (int j = 0; j < 8; ++j) s[j] += bfs_to_f(v[j]);
    }

    __shared__ float red[4][512];
    __shared__ float pooled[512];
#pragma unroll
    for (int j = 0; j < 8; ++j) red[nl][dl * 8 + j] = s[j];
    __syncthreads();
    if (nl == 0) {
#pragma unroll
        for (int j = 0; j < 8; ++j) {
            const int d = dl * 8 + j;
            pooled[d] = (red[0][d] + red[1][d] + red[2][d] + red[3][d]) * invc;
        }
    }
    __syncthreads();

    float val = 0.f;
    if (threadIdx.x < 128) {
        const int j = threadIdx.x;
        float acc = 0.f;
        for (int i = 0; i < D_FUSED; ++i) acc = fmaf(pooled[i], w1[i * HID + j], acc);
        const float hid = fmaxf(acc + b1[j], 0.f);
        val = hid * w2[j];
    }
#pragma unroll
    for (int o = 32; o; o >>= 1) val += __shfl_xor(val, o);
    __shared__ float ws2[2];
    if ((threadIdx.x & 63) == 0 && threadIdx.x < 128) ws2[threadIdx.x >> 6] = val;
    __syncthreads();
    if (threadIdx.x == 0) {
        const float sum = ws2[0] + ws2[1] + b2[0];
        out[g] = 1.f / (1.f + __expf(-sum));
    }
}

// ---------------------------------------------------------------------------
extern "C" void kernel_launch(void* const* d_in, const int* in_sizes, int n_in,
                              void* d_out, int out_size, void* d_ws, size_t ws_size,
                              hipStream_t stream)
{
    const float* x        = (const float*)d_in[0];
    const int*   ei       = (const int*)d_in[1];
    const int*   batch    = (const int*)d_in[2];
    const float* syn_w    = (const float*)d_in[3];
    const float* syn_b    = (const float*)d_in[4];
    const float* ant_w    = (const float*)d_in[5];
    const float* ant_b    = (const float*)d_in[6];
    const float* fusion_w = (const float*)d_in[7];
    const float* fusion_b = (const float*)d_in[8];
    const float* Wq       = (const float*)d_in[9];
    const float* bq       = (const float*)d_in[10];
    const float* Wk       = (const float*)d_in[11];
    const float* bk       = (const float*)d_in[12];
    const float* Wv       = (const float*)d_in[13];
    const float* bv       = (const float*)d_in[14];
    const float* Wskip    = (const float*)d_in[15];
    const float* bskip    = (const float*)d_in[16];
    const float* cls_w1   = (const float*)d_in[17];
    const float* cls_b1   = (const float*)d_in[18];
    const float* cls_w2   = (const float*)d_in[19];
    const float* cls_b2   = (const float*)d_in[20];

    const int* src = ei;
    const int* dst = ei + N_EDGES;

    // ---- workspace layout (~125 MB) ----
    const size_t NV = (size_t)N_NODES * D_FUSED;
    bf16* hA    = (bf16*)d_ws;                         // N*512 bf16
    bf16* hB    = hA + NV;                             // N*512 bf16
    unsigned char* qkv = (unsigned char*)(hB + NV);    // N*1536 fp8 (q|k|v)
    bf16* wenc  = (bf16*)(qkv + (size_t)N_NODES * 1536);     // 256*320
    bf16* wfus  = wenc + 256 * KPAD;                   // 512*256
    bf16* wcomb = wfus + 512 * 256;                    // 3*2048*512
    float* benc = (float*)(wcomb + (size_t)3 * 2048 * 512);  // 256
    float* bcomb = benc + 256;                         // 6144
    int* deg    = (int*)(bcomb + 6144);                // N
    int* cursor = deg + N_NODES;                       // N
    int* part   = cursor + N_NODES;                    // 128
    int* off    = part + 128;                          // N+1
    int* csr    = off + N_NODES + 1;                   // E

    bf16* xb   = (bf16*)qkv;  // N*320 bf16, dead before layer GEMMs
    bf16* tenc = hB;          // N*256, dead before first layer GEMM

    // ---- CSR build (cursor zeroed inside off_kernel) ----
    zero_int_kernel<<<(N_NODES + 255) / 256, 256, 0, stream>>>(deg, N_NODES);
    hist_kernel<<<N_EDGES / 256, 256, 0, stream>>>(dst, deg, N_EDGES);
    partial_sum_kernel<<<128, 256, 0, stream>>>(deg, part);
    scan_part_kernel<<<1, 128, 0, stream>>>(part);
    off_kernel<<<128, 256, 0, stream>>>(deg, part, off, cursor);
    scatter_kernel<<<N_EDGES / 256, 256, 0, stream>>>(src, dst, off, cursor, csr, N_EDGES);

    // ---- prep ----
    prep_xpad_kernel<<<(N_NODES * 80) / 256, 256, 0, stream>>>(x, xb);
    prep_encw_kernel<<<256, KPAD, 0, stream>>>(syn_w, ant_w, wenc);
    prep_fusw_kernel<<<512, 256, 0, stream>>>(fusion_w, wfus);
    prep_combw_kernel<<<3072, 256, 0, stream>>>(Wskip, Wq, Wk, Wv, wcomb);
    prep_bias_kernel<<<25, 256, 0, stream>>>(syn_b, ant_b, bskip, bq, bk, bv, benc, bcomb);

    // ---- encoder ----
    mfma_gemm<1><<<dim3(N_NODES / 128, 2), 256, 0, stream>>>(
        xb, KPAD, wenc, benc, tenc, 256, KPAD);
    mfma_gemm128<256, 0, 0><<<512, 512, 0, stream>>>(
        tenc, 256, wfus, fusion_b, hA, D_FUSED, hA, D_FUSED, D_FUSED, nullptr, 2);

    // ---- transformer layers ----
    bf16* hcur = hA;
    bf16* hnew = hB;
    for (int l = 0; l < N_LAYERS; ++l) {
        mfma_gemm128<512, 0, 1><<<2048, 512, 0, stream>>>(
            hcur, D_FUSED, wcomb + (size_t)l * 2048 * D_FUSED,
            bcomb + (size_t)l * 2048,
            hnew, D_FUSED, nullptr, 0, 512, qkv, 8);
        attn_kernel<<<N_NODES, 256, 0, stream>>>(qkv, hnew, off, csr);
        bf16* tmp = hcur; hcur = hnew; hnew = tmp;
    }

    // ---- fused pool + classify ----
    pool_cls_kernel<<<N_GRAPHS, 256, 0, stream>>>(hcur, batch, cls_w1, cls_b1,
                                                  cls_w2, cls_b2, (float*)d_out);
}